// Round 10
// baseline (1084.814 us; speedup 1.0000x reference)
//
#include <hip/hip_runtime.h>
#include <hip/hip_bf16.h>
#include <cstdint>

#define B_ 2
#define S_ 2048
#define H_ 2048
#define NH_ 16
#define QL_ 1536
#define KVL_ 512
#define NOPE_ 128
#define ROPE_ 64
#define QHD_ 192
#define VHD_ 128
#define FF_ 8192
#define BS_ (B_ * S_)            // 4096 rows
#define CKVP_ 640                // padded ckv width (576 -> 640 for N%128==0)
#define KVW_ (NOPE_ + VHD_)      // 256 per head

typedef __hip_bfloat16 bf16;
typedef __attribute__((ext_vector_type(8))) short short8_t;  // 8 bf16 (4 VGPRs)
typedef __attribute__((ext_vector_type(4))) float f32x4;

__device__ __forceinline__ float ldf(const float* p, size_t i) { return p[i]; }
__device__ __forceinline__ float ldf(const bf16* p, size_t i) { return __bfloat162float(p[i]); }
__device__ __forceinline__ void stf(float* p, size_t i, float v) { p[i] = v; }
__device__ __forceinline__ void stf(bf16* p, size_t i, float v) { p[i] = __float2bfloat16(v); }

__device__ __forceinline__ void gload16(const void* g, void* l)
{
    __builtin_amdgcn_global_load_lds((const unsigned int*)g, (unsigned int*)l, 16, 0, 0);
}

// ---------------------------------------------------------------------------
// Transpose + convert: in fp32 [K][N] -> out bf16 [Npad][K]; rows n>=N zeroed.
// ---------------------------------------------------------------------------
__global__ __launch_bounds__(256) void transp_bf16(
    const float* __restrict__ in, bf16* __restrict__ out, int K, int N, int Npad)
{
    __shared__ float t[32][33];
    const int n0 = blockIdx.x * 32, k0 = blockIdx.y * 32;
    for (int r = threadIdx.y; r < 32; r += 8) {
        const int n = n0 + threadIdx.x;
        t[r][threadIdx.x] = (n < N) ? in[(size_t)(k0 + r) * N + n] : 0.f;
    }
    __syncthreads();
    for (int r = threadIdx.y; r < 32; r += 8) {
        out[(size_t)(n0 + r) * K + k0 + threadIdx.x] = __float2bfloat16(t[threadIdx.x][r]);
    }
}

// ---------------------------------------------------------------------------
// RMSNorm (templated dtypes): one 256-thread block per row.
// ---------------------------------------------------------------------------
template<typename InT, typename OutT>
__global__ __launch_bounds__(256) void rmsnorm2(
    const InT* __restrict__ in, const float* __restrict__ w,
    OutT* __restrict__ out, int cols, int istride, int ostride)
{
    const int row = blockIdx.x;
    const InT* ip = in + (size_t)row * istride;
    OutT* op = out + (size_t)row * ostride;

    float ss = 0.f;
    for (int c = threadIdx.x; c < cols; c += 256) {
        float v = ldf(ip, c);
        ss = fmaf(v, v, ss);
    }
    #pragma unroll
    for (int off = 32; off; off >>= 1) ss += __shfl_xor(ss, off);
    __shared__ float red[4];
    if ((threadIdx.x & 63) == 0) red[threadIdx.x >> 6] = ss;
    __syncthreads();
    const float total = red[0] + red[1] + red[2] + red[3];
    const float scale = rsqrtf(total / (float)cols + 1e-6f);
    for (int c = threadIdx.x; c < cols; c += 256) {
        stf(op, c, ldf(ip, c) * scale * w[c]);
    }
}

// ---------------------------------------------------------------------------
// 128x128 2-phase GEMM (m97 structure) — used for kva (N=640).
// ---------------------------------------------------------------------------
template<int MODE, typename OutT>
__global__ __launch_bounds__(256) void gemm_bf16(
    const bf16* __restrict__ A, const bf16* __restrict__ BT,
    const float* __restrict__ Df, const bf16* __restrict__ Db,
    OutT* __restrict__ C, int M, int N, int K)
{
    __shared__ short As[128 * 32];
    __shared__ short Bs[128 * 32];
    const int tid = threadIdx.x;
    const int wid = tid >> 6, lane = tid & 63;
    const int bm = blockIdx.y * 128, bn = blockIdx.x * 128;
    const int wr = (wid >> 1) * 64, wc = (wid & 1) * 64;
    const int l16 = lane & 15;
    const int lk = (lane >> 4) << 3;

    f32x4 acc[4][4] = {};

    for (int k0 = 0; k0 < K; k0 += 32) {
        #pragma unroll
        for (int is = 0; is < 2; ++is) {
            const int c = is * 256 + tid;
            const int row = c >> 2;
            const int cb = (c & 3) * 16;
            const char* srcA = (const char*)A + ((size_t)(bm + row) * K + k0) * 2 + cb;
            const char* srcB = (const char*)BT + ((size_t)(bn + row) * K + k0) * 2 + cb;
            char* dstA = (char*)As + (is * 256 + wid * 64) * 16;
            char* dstB = (char*)Bs + (is * 256 + wid * 64) * 16;
            gload16(srcA, dstA);
            gload16(srcB, dstB);
        }
        __syncthreads();

        short8_t a[4], b[4];
        const short* ApW = As + (wr + l16) * 32 + lk;
        const short* BpW = Bs + (wc + l16) * 32 + lk;
        #pragma unroll
        for (int m = 0; m < 4; ++m) a[m] = *(const short8_t*)(ApW + m * 16 * 32);
        #pragma unroll
        for (int n = 0; n < 4; ++n) b[n] = *(const short8_t*)(BpW + n * 16 * 32);
        #pragma unroll
        for (int m = 0; m < 4; ++m)
            #pragma unroll
            for (int n = 0; n < 4; ++n)
                acc[m][n] = __builtin_amdgcn_mfma_f32_16x16x32_bf16(a[m], b[n], acc[m][n], 0, 0, 0);
        __syncthreads();
    }

    const int r0 = bm + wr + ((lane >> 4) << 2);
    const int c0 = bn + wc + l16;
    #pragma unroll
    for (int m = 0; m < 4; ++m) {
        #pragma unroll
        for (int n = 0; n < 4; ++n) {
            const int row = r0 + m * 16;
            const int col = c0 + n * 16;
            #pragma unroll
            for (int r = 0; r < 4; ++r) {
                const size_t off = (size_t)(row + r) * N + col;
                float v = acc[m][n][r];
                if (MODE == 1) v += Df[off];
                if (MODE == 2) {
                    const float g = __bfloat162float(Db[off]);
                    v *= g / (1.f + __expf(-g));
                }
                stf(C, off, v);
            }
        }
    }
}

// ---------------------------------------------------------------------------
// Ring-GEMM helpers. LDS slot layout per region (chunk-interleaved):
//   byte addr of (row, chunk c of 4) = (row>>3)*512 + c*128 + (row&7)*16
// Frag reads (16 lanes, consecutive rows, fixed k-half) are LINEAR -> no
// bank conflicts, no XOR. Stage decode from linear LDS chunk index i:
//   row = (i>>5)*8 + (i&7), chunk = (i>>3)&3.
// ---------------------------------------------------------------------------
__device__ __forceinline__ short8_t ring_frag(const short* region, int row, int hk)
{
    return *(const short8_t*)(region + ((row >> 3) << 8) + (hk << 6) + ((row & 7) << 3));
}

template<int MODE, typename OutT>
__device__ __forceinline__ void epi_store(
    OutT* __restrict__ C, const float* __restrict__ Df, const bf16* __restrict__ Db,
    int N, int row, int col, float v)
{
    const size_t off = (size_t)row * N + col;
    if (MODE == 1) v += Df[off];
    if (MODE == 2) {
        const float g = __bfloat162float(Db[off]);
        v *= g / (1.f + __expf(-g));
    }
    stf(C, off, v);
}

// ---------------------------------------------------------------------------
// 256x256 ring GEMM: 4-slot BK=32 ring (slot 32 KiB = A 16K + B 16K), one
// barrier per K-step, counted vmcnt (8/4/0), load-issue inside phases.
// 8 waves (2M x 4N), per-wave 128x64, 32 MFMA/step.
// ---------------------------------------------------------------------------
template<int MODE, typename OutT>
__global__ __launch_bounds__(512, 2) void gemm256(
    const bf16* __restrict__ A, const bf16* __restrict__ BT,
    const float* __restrict__ Df, const bf16* __restrict__ Db,
    OutT* __restrict__ C, int M, int N, int K)
{
    __shared__ short lds[4 * 16384];   // 128 KiB

    const int tid = threadIdx.x;
    const int wid = tid >> 6, lane = tid & 63;
    const int wm = wid >> 2, wn = wid & 3;
    const int l16 = lane & 15, hk = lane >> 4;

    const int nwg = gridDim.x * gridDim.y;
    const int orig = blockIdx.y * gridDim.x + blockIdx.x;
    const int q = nwg >> 3, r8 = nwg & 7;
    const int xcd = orig & 7, lid = orig >> 3;
    const int wg = (xcd < r8 ? xcd * (q + 1) : r8 * (q + 1) + (xcd - r8) * q) + lid;
    const int bn = (wg % gridDim.x) * 256;
    const int bm = (wg / gridDim.x) * 256;

    f32x4 acc[8][4] = {};
    const int nt = K >> 5;

    auto stage_step = [&](int s) {
        short* base = &lds[(s & 3) * 16384];
        const bf16* ga = A + (size_t)bm * K + s * 32;
        const bf16* gb = BT + (size_t)bn * K + s * 32;
        #pragma unroll
        for (int j = 0; j < 2; ++j) {
            const int i = j * 512 + tid;
            const int row = ((i >> 5) << 3) | (i & 7);
            const int ch = (i >> 3) & 3;
            gload16(ga + (size_t)row * K + ch * 8, (char*)base + i * 16);
            gload16(gb + (size_t)row * K + ch * 8, (char*)(base + 8192) + i * 16);
        }
    };

    stage_step(0); stage_step(1); stage_step(2);

    for (int s = 0; s < nt; ++s) {
        if (s + 2 < nt)      asm volatile("s_waitcnt vmcnt(8)" ::: "memory");
        else if (s + 1 < nt) asm volatile("s_waitcnt vmcnt(4)" ::: "memory");
        else                 asm volatile("s_waitcnt vmcnt(0)" ::: "memory");
        __builtin_amdgcn_s_barrier();

        const short* As = &lds[(s & 3) * 16384];
        const short* Bs = As + 8192;
        short8_t a[8], b[4];
        #pragma unroll
        for (int mf = 0; mf < 8; ++mf) a[mf] = ring_frag(As, wm * 128 + mf * 16 + l16, hk);
        #pragma unroll
        for (int nf = 0; nf < 4; ++nf) b[nf] = ring_frag(Bs, wn * 64 + nf * 16 + l16, hk);

        if (s + 3 < nt) stage_step(s + 3);

        __builtin_amdgcn_s_setprio(1);
        #pragma unroll
        for (int mf = 0; mf < 8; ++mf)
            #pragma unroll
            for (int nf = 0; nf < 4; ++nf)
                acc[mf][nf] = __builtin_amdgcn_mfma_f32_16x16x32_bf16(
                    a[mf], b[nf], acc[mf][nf], 0, 0, 0);
        __builtin_amdgcn_s_setprio(0);
    }

    const int r0 = bm + wm * 128 + (lane >> 4) * 4;
    const int c0 = bn + wn * 64 + l16;
    #pragma unroll
    for (int mf = 0; mf < 8; ++mf)
        #pragma unroll
        for (int nf = 0; nf < 4; ++nf)
            #pragma unroll
            for (int r = 0; r < 4; ++r)
                epi_store<MODE>(C, Df, Db, N, r0 + mf * 16 + r, c0 + nf * 16, acc[mf][nf][r]);
}

// ---------------------------------------------------------------------------
// 256x128 ring GEMM: slot 24 KiB (A 16K + B 8K), ring 96 KiB, LPT=3 ->
// vmcnt(6/3/0). 8 waves (4M x 2N), per-wave 64x64, 16 MFMA/step.
// ---------------------------------------------------------------------------
template<int MODE, typename OutT>
__global__ __launch_bounds__(512, 2) void gemm256n128(
    const bf16* __restrict__ A, const bf16* __restrict__ BT,
    const float* __restrict__ Df, const bf16* __restrict__ Db,
    OutT* __restrict__ C, int M, int N, int K)
{
    __shared__ short lds[4 * 12288];   // 96 KiB

    const int tid = threadIdx.x;
    const int wid = tid >> 6, lane = tid & 63;
    const int wm = wid >> 1, wn = wid & 1;
    const int l16 = lane & 15, hk = lane >> 4;

    const int nwg = gridDim.x * gridDim.y;
    const int orig = blockIdx.y * gridDim.x + blockIdx.x;
    const int q = nwg >> 3, r8 = nwg & 7;
    const int xcd = orig & 7, lid = orig >> 3;
    const int wg = (xcd < r8 ? xcd * (q + 1) : r8 * (q + 1) + (xcd - r8) * q) + lid;
    const int bn = (wg % gridDim.x) * 128;
    const int bm = (wg / gridDim.x) * 256;

    f32x4 acc[4][4] = {};
    const int nt = K >> 5;

    auto stage_step = [&](int s) {
        short* base = &lds[(s & 3) * 12288];
        const bf16* ga = A + (size_t)bm * K + s * 32;
        const bf16* gb = BT + (size_t)bn * K + s * 32;
        #pragma unroll
        for (int j = 0; j < 2; ++j) {
            const int i = j * 512 + tid;
            const int row = ((i >> 5) << 3) | (i & 7);
            const int ch = (i >> 3) & 3;
            gload16(ga + (size_t)row * K + ch * 8, (char*)base + i * 16);
        }
        {
            const int i = tid;
            const int row = ((i >> 5) << 3) | (i & 7);
            const int ch = (i >> 3) & 3;
            gload16(gb + (size_t)row * K + ch * 8, (char*)(base + 8192) + i * 16);
        }
    };

    stage_step(0); stage_step(1); stage_step(2);

    for (int s = 0; s < nt; ++s) {
        if (s + 2 < nt)      asm volatile("s_waitcnt vmcnt(6)" ::: "memory");
        else if (s + 1 < nt) asm volatile("s_waitcnt vmcnt(3)" ::: "memory");
        else                 asm volatile("s_waitcnt vmcnt(0)" ::: "memory");
        __builtin_amdgcn_s_barrier();

        const short* As = &lds[(s & 3) * 12288];
        const short* Bs = As + 8192;
        short8_t a[4], b[4];
        #pragma unroll
        for (int mf = 0; mf < 4; ++mf) a[mf] = ring_frag(As, wm * 64 + mf * 16 + l16, hk);
        #pragma unroll
        for (int nf = 0; nf < 4; ++nf) b[nf] = ring_frag(Bs, wn * 64 + nf * 16 + l16, hk);

        if (s + 3 < nt) stage_step(s + 3);

        __builtin_amdgcn_s_setprio(1);
        #pragma unroll
        for (int mf = 0; mf < 4; ++mf)
            #pragma unroll
            for (int nf = 0; nf < 4; ++nf)
                acc[mf][nf] = __builtin_amdgcn_mfma_f32_16x16x32_bf16(
                    a[mf], b[nf], acc[mf][nf], 0, 0, 0);
        __builtin_amdgcn_s_setprio(0);
    }

    const int r0 = bm + wm * 64 + (lane >> 4) * 4;
    const int c0 = bn + wn * 64 + l16;
    #pragma unroll
    for (int mf = 0; mf < 4; ++mf)
        #pragma unroll
        for (int nf = 0; nf < 4; ++nf)
            #pragma unroll
            for (int r = 0; r < 4; ++r)
                epi_store<MODE>(C, Df, Db, N, r0 + mf * 16 + r, c0 + nf * 16, acc[mf][nf][r]);
}

// ---------------------------------------------------------------------------
// Fused gate+up ring GEMM: C = silu(A@BG^T) * (A@BU^T). 256x128 tile,
// slot 32 KiB (A 16K + BG 8K + BU 8K), LPT=4 -> vmcnt(8/4/0).
// 8 waves (4M x 2N), per-wave 64x64 dual acc, 32 MFMA/step.
// Column-major block walk (consecutive blocks share B panels).
// ---------------------------------------------------------------------------
__global__ __launch_bounds__(512, 2) void gemm256dual(
    const bf16* __restrict__ A, const bf16* __restrict__ BG,
    const bf16* __restrict__ BU, bf16* __restrict__ C, int M, int N, int K)
{
    __shared__ short lds[4 * 16384];   // 128 KiB

    const int tid = threadIdx.x;
    const int wid = tid >> 6, lane = tid & 63;
    const int wm = wid >> 1, wn = wid & 1;
    const int l16 = lane & 15, hk = lane >> 4;

    const int nwg = gridDim.x * gridDim.y;
    const int orig = blockIdx.y * gridDim.x + blockIdx.x;
    const int q = nwg >> 3, r8 = nwg & 7;
    const int xcd = orig & 7, lid = orig >> 3;
    const int wg = (xcd < r8 ? xcd * (q + 1) : r8 * (q + 1) + (xcd - r8) * q) + lid;
    const int bm = (wg % gridDim.y) * 256;
    const int bn = (wg / gridDim.y) * 128;

    f32x4 ag[4][4] = {}, au[4][4] = {};
    const int nt = K >> 5;

    auto stage_step = [&](int s) {
        short* base = &lds[(s & 3) * 16384];
        const bf16* ga = A + (size_t)bm * K + s * 32;
        const bf16* gg = BG + (size_t)bn * K + s * 32;
        const bf16* gu = BU + (size_t)bn * K + s * 32;
        #pragma unroll
        for (int j = 0; j < 2; ++j) {
            const int i = j * 512 + tid;
            const int row = ((i >> 5) << 3) | (i & 7);
            const int ch = (i >> 3) & 3;
            gload16(ga + (size_t)row * K + ch * 8, (char*)base + i * 16);
        }
        {
            const int i = tid;
            const int row = ((i >> 5) << 3) | (i & 7);
            const int ch = (i >> 3) & 3;
            gload16(gg + (size_t)row * K + ch * 8, (char*)(base + 8192) + i * 16);
            gload16(gu + (size_t)row * K + ch * 8, (char*)(base + 12288) + i * 16);
        }
    };

    stage_step(0); stage_step(1); stage_step(2);

    for (int s = 0; s < nt; ++s) {
        if (s + 2 < nt)      asm volatile("s_waitcnt vmcnt(8)" ::: "memory");
        else if (s + 1 < nt) asm volatile("s_waitcnt vmcnt(4)" ::: "memory");
        else                 asm volatile("s_waitcnt vmcnt(0)" ::: "memory");
        __builtin_amdgcn_s_barrier();

        const short* As = &lds[(s & 3) * 16384];
        const short* Gs = As + 8192;
        const short* Us = As + 12288;
        short8_t a[4], g[4], u[4];
        #pragma unroll
        for (int mf = 0; mf < 4; ++mf) a[mf] = ring_frag(As, wm * 64 + mf * 16 + l16, hk);
        #pragma unroll
        for (int nf = 0; nf < 4; ++nf) {
            g[nf] = ring_frag(Gs, wn * 64 + nf * 16 + l16, hk);
            u[nf] = ring_frag(Us, wn * 64 + nf * 16 + l16, hk);
        }

        if (s + 3 < nt) stage_step(s + 3);

        __builtin_amdgcn_s_setprio(1);
        #pragma unroll
        for (int mf = 0; mf < 4; ++mf)
            #pragma unroll
            for (int nf = 0; nf < 4; ++nf) {
                ag[mf][nf] = __builtin_amdgcn_mfma_f32_16x16x32_bf16(
                    a[mf], g[nf], ag[mf][nf], 0, 0, 0);
                au[mf][nf] = __builtin_amdgcn_mfma_f32_16x16x32_bf16(
                    a[mf], u[nf], au[mf][nf], 0, 0, 0);
            }
        __builtin_amdgcn_s_setprio(0);
    }

    const int r0 = bm + wm * 64 + (lane >> 4) * 4;
    const int c0 = bn + wn * 64 + l16;
    #pragma unroll
    for (int mf = 0; mf < 4; ++mf)
        #pragma unroll
        for (int nf = 0; nf < 4; ++nf)
            #pragma unroll
            for (int r = 0; r < 4; ++r) {
                const float gg = ag[mf][nf][r];
                const float uu = au[mf][nf][r];
                const float v = gg / (1.f + __expf(-gg)) * uu;
                C[(size_t)(r0 + mf * 16 + r) * N + c0 + nf * 16] = __float2bfloat16(v);
            }
}

// ---------------------------------------------------------------------------
// RoPE: one wave per 64-dim slice. q bf16 (B,S,NH,192), k_pe fp32 in ckv.
// ---------------------------------------------------------------------------
__global__ __launch_bounds__(256) void rope_kernel(
    bf16* __restrict__ q, float* __restrict__ ckv,
    const int* __restrict__ pos_ids,
    const float* __restrict__ sinT, const float* __restrict__ cosT)
{
    const int wid = blockIdx.x * 4 + (threadIdx.x >> 6);
    const int lane = threadIdx.x & 63;
    const int NQ = BS_ * NH_;

    int bs;
    bf16* bptr = nullptr;
    float* fptr = nullptr;
    if (wid < NQ) {
        bs = wid >> 4;
        bptr = q + (size_t)wid * QHD_ + NOPE_;
    } else {
        bs = wid - NQ;
        fptr = ckv + (size_t)bs * CKVP_ + KVL_;
    }
    const int pos = pos_ids[bs];
    const float c  = cosT[pos * ROPE_ + lane];
    const float sn = sinT[pos * ROPE_ + lane];
    const float x = bptr ? __bfloat162float(bptr[lane]) : fptr[lane];
    const int j = lane & 31;
    const float x0 = __shfl(x, 2 * j);
    const float x1 = __shfl(x, 2 * j + 1);
    const float res = (lane < 32) ? fmaf(x0, c, -x1 * sn) : fmaf(x1, c, x0 * sn);
    if (bptr) bptr[lane] = __float2bfloat16(res);
    else      fptr[lane] = res;
}

// ---------------------------------------------------------------------------
// pack_k: Kh (B,NH,S,192) bf16 <- k_nope from KV fp32 + rope'd k_pe from CKV.
// ---------------------------------------------------------------------------
__global__ __launch_bounds__(256) void pack_k(
    const float* __restrict__ KV, const float* __restrict__ CKV,
    bf16* __restrict__ Kh)
{
    const int total = BS_ * NH_ * (QHD_ / 2);
    for (int i = blockIdx.x * 256 + threadIdx.x; i < total; i += gridDim.x * 256) {
        const int d2 = i % (QHD_ / 2);
        const int t  = i / (QHD_ / 2);
        const int s  = t % S_;
        const int hh = (t / S_) % NH_;
        const int bb = t / (S_ * NH_);
        const int d = d2 * 2;
        float2 v;
        if (d < NOPE_) v = *(const float2*)&KV[(((size_t)bb * S_ + s) * NH_ + hh) * KVW_ + d];
        else           v = *(const float2*)&CKV[((size_t)bb * S_ + s) * CKVP_ + KVL_ + (d - NOPE_)];
        union { bf16 h[2]; unsigned int u; } cv;
        cv.h[0] = __float2bfloat16(v.x);
        cv.h[1] = __float2bfloat16(v.y);
        *(unsigned int*)&Kh[((size_t)(bb * NH_ + hh) * S_ + s) * QHD_ + d] = cv.u;
    }
}

// ---------------------------------------------------------------------------
// pack_vt: Vt (B,NH,128,S) bf16 <- V = KV[...,128:256] fp32, transposed.
// ---------------------------------------------------------------------------
__global__ __launch_bounds__(256) void pack_vt(
    const float* __restrict__ KV, bf16* __restrict__ Vt)
{
    __shared__ float t[32][33];
    const int s0 = blockIdx.x * 32, d0 = blockIdx.y * 32;
    const int bh = blockIdx.z;
    const int tx = threadIdx.x & 31, ty = threadIdx.x >> 5;
    for (int r = ty; r < 32; r += 8)
        t[r][tx] = KV[(((size_t)(bh >> 4) * S_ + s0 + r) * NH_ + (bh & 15)) * KVW_ + NOPE_ + d0 + tx];
    __syncthreads();
    for (int r = ty; r < 32; r += 8)
        Vt[((size_t)bh * VHD_ + d0 + r) * S_ + s0 + tx] = __float2bfloat16(t[tx][r]);
}

// ---------------------------------------------------------------------------
// MFMA flash attention v4 — paired blocks (balance) + XCD-chunked heads
// (L2 locality) + no-spill register budget (launch_bounds 512,2).
// ---------------------------------------------------------------------------
__global__ __launch_bounds__(512, 2) void attn_mfma(
    const bf16* __restrict__ Qp, const bf16* __restrict__ Kh,
    const bf16* __restrict__ Vt, bf16* __restrict__ outp)
{
    __shared__ __align__(16) short Ks[64][192];    // 24 chunks/row, XOR-swizzled
    __shared__ __align__(16) short Vs[128][64];    // 8 chunks/row, XOR-swizzled
    __shared__ __align__(16) short Ps[8][16][64];  // per-wave, XOR-swizzled

    const int tid = threadIdx.x;
    const int wid = tid >> 6, lane = tid & 63;
    const int l16 = lane & 15;
    const int hk  = lane >> 4;          // 0..3
    const int lk  = hk << 3;
    const int pr  = hk << 2;
    const int lx  = l16 & 7;

    const int bid = blockIdx.x;
    const int orig = (bid & 7) * 64 + (bid >> 3);
    const int j  = orig & 15;           // pair index
    const int gh = orig >> 4;           // 0..31
    const int h = gh & 15, b = gh >> 4;

    const int setB = wid >> 2;
    const int qblk = setB ? (31 - j) : j;
    const int qw = qblk * 64 + (wid & 3) * 16;
    const int myNt = qblk + 1;
    const int ntStage = 32 - j;

    short8_t qf[6];
    const bf16* qbase = Qp + (((size_t)b * S_ + qw + l16) * NH_ + h) * QHD_;
    #pragma unroll
    for (int kk = 0; kk < 6; ++kk)
        qf[kk] = *(const short8_t*)(qbase + kk * 32 + lk);

    const bf16* Khb = Kh + (size_t)(b * NH_ + h) * S_ * QHD_;
    const bf16* Vtb = Vt + (size_t)(b * NH_ + h) * VHD_ * S_;

    f32x4 o[8] = {};
    float mr[4] = {-3.0e38f, -3.0e38f, -3.0e38f, -3.0e38f};
    float lr[4] = {0.f, 0.f, 0.f, 0.f};
    const float scale = 0.07216878364870323f;  // 192^-0.5

    const int krow = tid >> 3, kc0 = (tid & 7) * 3;
    const int vrow = tid >> 2, vc0 = (tid & 3) * 2;

    short8_t kreg[3], vreg[2];
    auto load_tile = [&](int kt) {
        const short* ksrc = (const short*)(Khb + ((size_t)(kt * 64 + krow)) * QHD_);
        kreg[0] = *(const short8_t*)(ksrc + (kc0 + 0) * 8);
        kreg[1] = *(const short8_t*)(ksrc + (kc0 + 1) * 8);
        kreg[2] = *(const short8_t*)(ksrc + (kc0 + 2) * 8);
        const short* vsrc = (const short*)(Vtb + (size_t)vrow * S_ + kt * 64);
        vreg[0] = *(const short8_t*)(vsrc + (vc0 + 0) * 8);
        vreg[1] = *(const short8_t*)(vsrc + (vc0 + 1) * 8);
    };
    auto write_tile = [&]() {
        const int kx = krow & 7, vx = vrow & 7;
        *(short8_t*)&Ks[krow][((kc0 + 0) ^ kx) << 3] = kreg[0];
        *(short8_t*)&Ks[krow][((kc0 + 1) ^ kx) << 3] = kreg[1];
        *(short8_t*)&Ks[krow][((kc0 + 2) ^ kx) << 3] = kreg[2];
        *(short8_t*)&Vs[vrow][((vc0 + 0) ^ vx) << 3] = vreg[0];
        *(short8_t*)&Vs[vrow][((vc0 + 1) ^ vx) << 3] = vreg[1];
    };

    load_tile(0);

    for (int t = 0; t < ntStage; ++t) {
        write_tile();
        __syncthreads();
        if (t + 1 < ntStage) load_tile(t + 1);
        if (t < myNt) {
            const int k0 = t << 6;
            f32x4 s[4] = {};
            #pragma unroll
            for (int kk = 0; kk < 6; ++kk) {
                #pragma unroll
                for (int n = 0; n < 4; ++n) {
                    short8_t kf = *(const short8_t*)&Ks[n * 16 + l16][((kk * 4 + hk) ^ lx) << 3];
                    s[n] = __builtin_amdgcn_mfma_f32_16x16x32_bf16(qf[kk], kf, s[n], 0, 0, 0);
                }
            }
            if (t == myNt - 1) {
                #pragma unroll
                for (int n = 0; n < 4; ++n) {
                    const int kg = k0 + n * 16 + l16;
                    #pragma unroll
                    for (int r = 0; r < 4; ++r) {
                        if (kg > qw + pr + r) s[n][r] = -3.0e38f;
                    }
                }
            }
            #pragma unroll
            for (int r = 0; r < 4; ++r) {
                float rm = fmaxf(fmaxf(s[0][r], s[1][r]), fmaxf(s[2][r], s[3][r]));
                rm = fmaxf(rm, __shfl_xor(rm, 1));
                rm = fmaxf(rm, __shfl_xor(rm, 2));
                rm = fmaxf(rm, __shfl_xor(rm, 4));
                rm = fmaxf(rm, __shfl_xor(rm, 8));
                const float mnew = fmaxf(mr[r], rm);
                const float corr = __expf((mr[r] - mnew) * scale);
                mr[r] = mnew;
                float rs = 0.f;
                #pragma unroll
                for (int n = 0; n < 4; ++n) {
                    const float p = __expf((s[n][r] - mnew) * scale);
                    s[n][r] = p;
                    rs += p;
                }
                rs += __shfl_xor(rs, 1);
                rs += __shfl_xor(rs, 2);
                rs += __shfl_xor(rs, 4);
                rs += __shfl_xor(rs, 8);
                lr[r] = lr[r] * corr + rs;
                #pragma unroll
                for (int n = 0; n < 8; ++n) o[n][r] *= corr;
            }
            #pragma unroll
            for (int n = 0; n < 4; ++n) {
                #pragma unroll
                for (int r = 0; r < 4; ++r) {
                    union { bf16 hh; short u; } cv;
                    cv.hh = __float2bfloat16(s[n][r]);
                    const int row = pr + r;
                    const int col = (((n * 2 + (l16 >> 3)) ^ (row & 7)) << 3) + (l16 & 7);
                    Ps[wid][row][col] = cv.u;
                }
            }
            #pragma unroll
            for (int kk2 = 0; kk2 < 2; ++kk2) {
                short8_t pf = *(const short8_t*)&Ps[wid][l16][((kk2 * 4 + hk) ^ lx) << 3];
                #pragma unroll
                for (int n = 0; n < 8; ++n) {
                    short8_t vf = *(const short8_t*)&Vs[n * 16 + l16][((kk2 * 4 + hk) ^ lx) << 3];
                    o[n] = __builtin_amdgcn_mfma_f32_16x16x32_bf16(pf, vf, o[n], 0, 0, 0);
                }
            }
        }
        __syncthreads();
    }

    float inv[4];
    #pragma unroll
    for (int r = 0; r < 4; ++r) inv[r] = 1.f / lr[r];
    bf16* ob = outp + (((size_t)b * S_ + qw + pr) * NH_ + h) * VHD_;
    #pragma unroll
    for (int r = 0; r < 4; ++r)
        #pragma unroll
        for (int n = 0; n < 8; ++n)
            ob[(size_t)r * (NH_ * VHD_) + n * 16 + l16] = __float2bfloat16(o[n][r] * inv[r]);
}

// ---------------------------------------------------------------------------
// Launch
// ---------------------------------------------------------------------------
extern "C" void kernel_launch(void* const* d_in, const int* in_sizes, int n_in,
                              void* d_out, int out_size, void* d_ws, size_t ws_size,
                              hipStream_t stream)
{
    const float* hidden  = (const float*)d_in[0];
    const float* ln1_w   = (const float*)d_in[1];
    const float* q_a_k   = (const float*)d_in[2];
    const float* q_a_ln  = (const float*)d_in[3];
    const float* q_b_k   = (const float*)d_in[4];
    const float* kv_a_k  = (const float*)d_in[5];
    const float* kv_a_ln = (const float*)d_in[6];
    const float* kv_b_k  = (const float*)d_in[7];
    const float* o_k     = (const float*)d_in[8];
    const float* ln2_w   = (const float*)d_in[9];
    const float* gate_k  = (const float*)d_in[10];
    const float* up_k    = (const float*)d_in[11];
    const float* down_k  = (const float*)d_in[12];
    const float* sinT    = (const float*)d_in[13];
    const float* cosT    = (const float*)d_in[14];
    const int*   pos     = (const int*)d_in[15];
    float* out = (float*)d_out;
    char* ws = (char*)d_ws;

    // ---- Phase-1 workspace layout ----
    bf16* qaT   = (bf16*)(ws + 0);            // [1536][2048]  6,291,456
    bf16* qbT   = (bf16*)(ws + 6291456);      // [3072][1536]  9,437,184
    bf16* kvaT  = (bf16*)(ws + 15728640);     // [640][2048]   2,621,440
    bf16* kvbT  = (bf16*)(ws + 18350080);     // [4096][512]   4,194,304
    bf16* oT    = (bf16*)(ws + 22544384);     // [2048][2048]  8,388,608
    bf16* Xb    = (bf16*)(ws + 30932992);     // [4096][2048] 16,777,216
    bf16* QAb   = (bf16*)(ws + 47710208);     // [4096][1536] 12,582,912
    bf16* CKVNb = (bf16*)(ws + 60293120);     // [4096][512]   4,194,304
    bf16* Qb    = (bf16*)(ws + 64487424);     // [4096][3072] 25,165,824
    float* CKV  = (float*)(ws + 89653248);    // [4096][640]  10,485,760
    float* KV   = (float*)(ws + 100139008);   // [4096][4096] 67,108,864
    bf16* ATTNb = (bf16*)(ws + 167247872);    // [4096][2048] 16,777,216
    bf16* Vt    = (bf16*)(ws + 0);            // overlays dead qaT/qbT/kvaT
    bf16* Kh    = (bf16*)(ws + 30932992);     // overlays dead Xb+QAb
    // ---- Phase-2 layout ----
    bf16* gateT = (bf16*)(ws + 0);            // [8192][2048] 33,554,432
    bf16* upT   = (bf16*)(ws + 33554432);     // [8192][2048] 33,554,432
    bf16* downT = (bf16*)(ws + 67108864);     // [2048][8192] 33,554,432
    bf16* X2b   = (bf16*)(ws + 100663296);    // [4096][2048] 16,777,216
    bf16* MLPb  = (bf16*)(ws + 117440512);    // [4096][8192] 67,108,864

    const dim3 tb(32, 8);

    // 0. weight transposes (attention-phase weights)
    transp_bf16<<<dim3(1536 / 32, 2048 / 32), tb, 0, stream>>>(q_a_k, qaT, 2048, 1536, 1536);
    transp_bf16<<<dim3(3072 / 32, 1536 / 32), tb, 0, stream>>>(q_b_k, qbT, 1536, 3072, 3072);
    transp_bf16<<<dim3(640 / 32, 2048 / 32), tb, 0, stream>>>(kv_a_k, kvaT, 2048, 576, 640);
    transp_bf16<<<dim3(4096 / 32, 512 / 32), tb, 0, stream>>>(kv_b_k, kvbT, 512, 4096, 4096);
    transp_bf16<<<dim3(2048 / 32, 2048 / 32), tb, 0, stream>>>(o_k, oT, 2048, 2048, 2048);

    // 1. Xb = rmsnorm(hidden)
    rmsnorm2<float, bf16><<<BS_, 256, 0, stream>>>(hidden, ln1_w, Xb, H_, H_, H_);
    // 2. QAb = Xb @ qaT   (ring 256x128, grid 12x16)
    gemm256n128<0, bf16><<<dim3(QL_ / 128, BS_ / 256), 512, 0, stream>>>(
        Xb, qaT, nullptr, nullptr, QAb, BS_, QL_, H_);
    // 3. QAb = rmsnorm(QAb) in place
    rmsnorm2<bf16, bf16><<<BS_, 256, 0, stream>>>(QAb, q_a_ln, QAb, QL_, QL_, QL_);
    // 4. Qb = QAb @ qbT   (ring 256x128, grid 24x16)
    gemm256n128<0, bf16><<<dim3((NH_ * QHD_) / 128, BS_ / 256), 512, 0, stream>>>(
        QAb, qbT, nullptr, nullptr, Qb, BS_, NH_ * QHD_, QL_);
    // 5. CKV = Xb @ kvaT (fp32, padded width 640; 128-tile)
    gemm_bf16<0, float><<<dim3(CKVP_ / 128, BS_ / 128), 256, 0, stream>>>(
        Xb, kvaT, nullptr, nullptr, CKV, BS_, CKVP_, H_);
    // 6. CKVNb = rmsnorm(CKV[:, :512])
    rmsnorm2<float, bf16><<<BS_, 256, 0, stream>>>(CKV, kv_a_ln, CKVNb, KVL_, CKVP_, KVL_);
    // 7. KV = CKVNb @ kvbT (fp32, ring 256x256, grid 16x16)
    gemm256<0, float><<<dim3((NH_ * KVW_) / 256, BS_ / 256), 512, 0, stream>>>(
        CKVNb, kvbT, nullptr, nullptr, KV, BS_, NH_ * KVW_, KVL_);
    // 8. RoPE in place on Qb and CKV k_pe
    rope_kernel<<<(BS_ * NH_ + BS_) / 4, 256, 0, stream>>>(Qb, CKV, pos, sinT, cosT);
    // 9. pack K and V^T into head-major bf16
    pack_k<<<2048, 256, 0, stream>>>(KV, CKV, Kh);
    pack_vt<<<dim3(S_ / 32, VHD_ / 32, B_ * NH_), 256, 0, stream>>>(KV, Vt);
    // 10. MFMA flash attention -> ATTNb
    attn_mfma<<<dim3(512), 512, 0, stream>>>(Qb, Kh, Vt, ATTNb);
    // 11. d_out = ATTNb @ oT + hidden (fp32, ring 256x128, grid 16x16)
    gemm256n128<1, float><<<dim3(H_ / 128, BS_ / 256), 512, 0, stream>>>(
        ATTNb, oT, hidden, nullptr, out, BS_, H_, NH_ * VHD_);

    // 12. MLP-phase weight transposes
    transp_bf16<<<dim3(8192 / 32, 2048 / 32), tb, 0, stream>>>(gate_k, gateT, 2048, 8192, 8192);
    transp_bf16<<<dim3(8192 / 32, 2048 / 32), tb, 0, stream>>>(up_k, upT, 2048, 8192, 8192);
    transp_bf16<<<dim3(2048 / 32, 8192 / 32), tb, 0, stream>>>(down_k, downT, 8192, 2048, 2048);

    // 13. X2b = rmsnorm(d_out)
    rmsnorm2<float, bf16><<<BS_, 256, 0, stream>>>(out, ln2_w, X2b, H_, H_, H_);
    // 14. MLPb = silu(X2b @ gateT) * (X2b @ upT)  — fused dual ring GEMM
    gemm256dual<<<dim3(FF_ / 128, BS_ / 256), 512, 0, stream>>>(
        X2b, gateT, upT, MLPb, BS_, FF_, H_);
    // 15. d_out = MLPb @ downT + d_out (ring 256x128, grid 16x16)
    gemm256n128<1, float><<<dim3(H_ / 128, BS_ / 256), 512, 0, stream>>>(
        MLPb, downT, out, nullptr, out, BS_, H_, FF_);
}

// Round 11
// 978.340 us; speedup vs baseline: 1.1088x; 1.1088x over previous
//
#include <hip/hip_runtime.h>
#include <hip/hip_bf16.h>
#include <cstdint>

#define B_ 2
#define S_ 2048
#define H_ 2048
#define NH_ 16
#define QL_ 1536
#define KVL_ 512
#define NOPE_ 128
#define ROPE_ 64
#define QHD_ 192
#define VHD_ 128
#define FF_ 8192
#define BS_ (B_ * S_)            // 4096 rows
#define CKVP_ 640                // padded ckv width (576 -> 640 for N%128==0)
#define KVW_ (NOPE_ + VHD_)      // 256 per head

typedef __hip_bfloat16 bf16;
typedef __attribute__((ext_vector_type(8))) short short8_t;  // 8 bf16 (4 VGPRs)
typedef __attribute__((ext_vector_type(4))) float f32x4;

__device__ __forceinline__ float ldf(const float* p, size_t i) { return p[i]; }
__device__ __forceinline__ float ldf(const bf16* p, size_t i) { return __bfloat162float(p[i]); }
__device__ __forceinline__ void stf(float* p, size_t i, float v) { p[i] = v; }
__device__ __forceinline__ void stf(bf16* p, size_t i, float v) { p[i] = __float2bfloat16(v); }

__device__ __forceinline__ void gload16(const void* g, void* l)
{
    __builtin_amdgcn_global_load_lds((const unsigned int*)g, (unsigned int*)l, 16, 0, 0);
}

// ---------------------------------------------------------------------------
// Transpose + convert: in fp32 [K][N] -> out bf16 [Npad][K]; rows n>=N zeroed.
// ---------------------------------------------------------------------------
__global__ __launch_bounds__(256) void transp_bf16(
    const float* __restrict__ in, bf16* __restrict__ out, int K, int N, int Npad)
{
    __shared__ float t[32][33];
    const int n0 = blockIdx.x * 32, k0 = blockIdx.y * 32;
    for (int r = threadIdx.y; r < 32; r += 8) {
        const int n = n0 + threadIdx.x;
        t[r][threadIdx.x] = (n < N) ? in[(size_t)(k0 + r) * N + n] : 0.f;
    }
    __syncthreads();
    for (int r = threadIdx.y; r < 32; r += 8) {
        out[(size_t)(n0 + r) * K + k0 + threadIdx.x] = __float2bfloat16(t[threadIdx.x][r]);
    }
}

// ---------------------------------------------------------------------------
// RMSNorm (templated dtypes): one 256-thread block per row.
// ---------------------------------------------------------------------------
template<typename InT, typename OutT>
__global__ __launch_bounds__(256) void rmsnorm2(
    const InT* __restrict__ in, const float* __restrict__ w,
    OutT* __restrict__ out, int cols, int istride, int ostride)
{
    const int row = blockIdx.x;
    const InT* ip = in + (size_t)row * istride;
    OutT* op = out + (size_t)row * ostride;

    float ss = 0.f;
    for (int c = threadIdx.x; c < cols; c += 256) {
        float v = ldf(ip, c);
        ss = fmaf(v, v, ss);
    }
    #pragma unroll
    for (int off = 32; off; off >>= 1) ss += __shfl_xor(ss, off);
    __shared__ float red[4];
    if ((threadIdx.x & 63) == 0) red[threadIdx.x >> 6] = ss;
    __syncthreads();
    const float total = red[0] + red[1] + red[2] + red[3];
    const float scale = rsqrtf(total / (float)cols + 1e-6f);
    for (int c = threadIdx.x; c < cols; c += 256) {
        stf(op, c, ldf(ip, c) * scale * w[c]);
    }
}

// ---------------------------------------------------------------------------
// 128x128 2-phase GEMM (m97 structure) — used for small-N shapes (qa, kva).
// ---------------------------------------------------------------------------
template<int MODE, typename OutT>
__global__ __launch_bounds__(256) void gemm_bf16(
    const bf16* __restrict__ A, const bf16* __restrict__ BT,
    const float* __restrict__ Df, const bf16* __restrict__ Db,
    OutT* __restrict__ C, int M, int N, int K)
{
    __shared__ short As[128 * 32];
    __shared__ short Bs[128 * 32];
    const int tid = threadIdx.x;
    const int wid = tid >> 6, lane = tid & 63;
    const int bm = blockIdx.y * 128, bn = blockIdx.x * 128;
    const int wr = (wid >> 1) * 64, wc = (wid & 1) * 64;
    const int l16 = lane & 15;
    const int lk = (lane >> 4) << 3;

    f32x4 acc[4][4] = {};

    for (int k0 = 0; k0 < K; k0 += 32) {
        #pragma unroll
        for (int is = 0; is < 2; ++is) {
            const int c = is * 256 + tid;
            const int row = c >> 2;
            const int cb = (c & 3) * 16;
            const char* srcA = (const char*)A + ((size_t)(bm + row) * K + k0) * 2 + cb;
            const char* srcB = (const char*)BT + ((size_t)(bn + row) * K + k0) * 2 + cb;
            char* dstA = (char*)As + (is * 256 + wid * 64) * 16;
            char* dstB = (char*)Bs + (is * 256 + wid * 64) * 16;
            gload16(srcA, dstA);
            gload16(srcB, dstB);
        }
        __syncthreads();

        short8_t a[4], b[4];
        const short* ApW = As + (wr + l16) * 32 + lk;
        const short* BpW = Bs + (wc + l16) * 32 + lk;
        #pragma unroll
        for (int m = 0; m < 4; ++m) a[m] = *(const short8_t*)(ApW + m * 16 * 32);
        #pragma unroll
        for (int n = 0; n < 4; ++n) b[n] = *(const short8_t*)(BpW + n * 16 * 32);
        #pragma unroll
        for (int m = 0; m < 4; ++m)
            #pragma unroll
            for (int n = 0; n < 4; ++n)
                acc[m][n] = __builtin_amdgcn_mfma_f32_16x16x32_bf16(a[m], b[n], acc[m][n], 0, 0, 0);
        __syncthreads();
    }

    const int r0 = bm + wr + ((lane >> 4) << 2);
    const int c0 = bn + wc + l16;
    #pragma unroll
    for (int m = 0; m < 4; ++m) {
        #pragma unroll
        for (int n = 0; n < 4; ++n) {
            const int row = r0 + m * 16;
            const int col = c0 + n * 16;
            #pragma unroll
            for (int r = 0; r < 4; ++r) {
                const size_t off = (size_t)(row + r) * N + col;
                float v = acc[m][n][r];
                if (MODE == 1) v += Df[off];
                if (MODE == 2) {
                    const float g = __bfloat162float(Db[off]);
                    v *= g / (1.f + __expf(-g));
                }
                stf(C, off, v);
            }
        }
    }
}

// ---------------------------------------------------------------------------
// Epilogue helper shared by the big GEMMs.
// ---------------------------------------------------------------------------
template<int MODE, typename OutT>
__device__ __forceinline__ void epi_store(
    OutT* __restrict__ C, const float* __restrict__ Df, const bf16* __restrict__ Db,
    int N, int row, int col, float v)
{
    const size_t off = (size_t)row * N + col;
    if (MODE == 1) v += Df[off];
    if (MODE == 2) {
        const float g = __bfloat162float(Db[off]);
        v *= g / (1.f + __expf(-g));
    }
    stf(C, off, v);
}

__device__ __forceinline__ short8_t ldsfrag(const short* half_base, int r, int c)
{
    return *(const short8_t*)(half_base + r * 64 + ((c ^ (r & 7)) << 3));
}

// ---------------------------------------------------------------------------
// 256x256 GEMM (R8 version): counted-vmcnt depth-2 pipeline, T2 swizzle, T5.
// 8 waves (2M x 4N), per-wave 128x64. LDS 128 KiB double-buffer.
// ---------------------------------------------------------------------------
template<int MODE, typename OutT>
__global__ __launch_bounds__(512, 2) void gemm256(
    const bf16* __restrict__ A, const bf16* __restrict__ BT,
    const float* __restrict__ Df, const bf16* __restrict__ Db,
    OutT* __restrict__ C, int M, int N, int K)
{
    __shared__ short lds[2][2][2][128 * 64];   // [buf][A/B][half] = 128 KiB

    const int tid = threadIdx.x;
    const int wid = tid >> 6, lane = tid & 63;
    const int wm = wid >> 2, wn = wid & 3;
    const int l16 = lane & 15, hk = lane >> 4;

    const int nwg = gridDim.x * gridDim.y;
    const int orig = blockIdx.y * gridDim.x + blockIdx.x;
    const int q = nwg >> 3, r8 = nwg & 7;
    const int xcd = orig & 7, lid = orig >> 3;
    const int wg = (xcd < r8 ? xcd * (q + 1) : r8 * (q + 1) + (xcd - r8) * q) + lid;
    const int bn = (wg % gridDim.x) * 256;
    const int bm = (wg / gridDim.x) * 256;

    f32x4 acc[8][4] = {};
    const int nt = K >> 6;

    auto stage_half = [&](const bf16* gbase, short* lbase) {
        #pragma unroll
        for (int i = 0; i < 2; ++i) {
            const int ch = i * 512 + tid;
            const int row = ch >> 3, pc = ch & 7;
            const int gc = pc ^ (row & 7);
            const char* src = (const char*)(gbase + (size_t)row * K + gc * 8);
            char* dst = (char*)lbase + (i * 512 + wid * 64) * 16;
            gload16(src, dst);
        }
    };
    auto stage_tile = [&](int t, int buf) {           // 8 loads / thread
        const int k0 = t << 6;
        stage_half(A + (size_t)bm * K + k0,          &lds[buf][0][0][0]);
        stage_half(A + (size_t)(bm + 128) * K + k0,  &lds[buf][0][1][0]);
        stage_half(BT + (size_t)bn * K + k0,         &lds[buf][1][0][0]);
        stage_half(BT + (size_t)(bn + 128) * K + k0, &lds[buf][1][1][0]);
    };

    stage_tile(0, 0);
    stage_tile(1, 1);
    asm volatile("s_waitcnt vmcnt(8)" ::: "memory");
    __builtin_amdgcn_s_barrier();

    int cur = 0;
    for (int t = 0; t < nt; ++t) {
        const short* Ah = &lds[cur][0][wm][0];
        const short* Bh = &lds[cur][1][wn >> 1][0];
        const int brr = (wn & 1) * 64;

        short8_t bfr[4][2], afr[2][2];

        #pragma unroll
        for (int ph = 0; ph < 4; ++ph) {
            if (ph == 0) {
                #pragma unroll
                for (int nf = 0; nf < 4; ++nf)
                    #pragma unroll
                    for (int ks = 0; ks < 2; ++ks)
                        bfr[nf][ks] = ldsfrag(Bh, brr + nf * 16 + l16, ks * 4 + hk);
            }
            #pragma unroll
            for (int mi = 0; mi < 2; ++mi)
                #pragma unroll
                for (int ks = 0; ks < 2; ++ks)
                    afr[mi][ks] = ldsfrag(Ah, ph * 32 + mi * 16 + l16, ks * 4 + hk);
            __builtin_amdgcn_s_barrier();
            __builtin_amdgcn_s_setprio(1);
            #pragma unroll
            for (int mi = 0; mi < 2; ++mi)
                #pragma unroll
                for (int nf = 0; nf < 4; ++nf)
                    #pragma unroll
                    for (int ks = 0; ks < 2; ++ks)
                        acc[ph * 2 + mi][nf] = __builtin_amdgcn_mfma_f32_16x16x32_bf16(
                            afr[mi][ks], bfr[nf][ks], acc[ph * 2 + mi][nf], 0, 0, 0);
            __builtin_amdgcn_s_setprio(0);
        }

        __builtin_amdgcn_s_barrier();
        if (t + 2 < nt) {
            stage_tile(t + 2, cur);
            asm volatile("s_waitcnt vmcnt(8)" ::: "memory");
        } else if (t + 1 < nt) {
            asm volatile("s_waitcnt vmcnt(0)" ::: "memory");
        }
        __builtin_amdgcn_s_barrier();
        cur ^= 1;
    }

    const int r0 = bm + wm * 128 + (lane >> 4) * 4;
    const int c0 = bn + wn * 64 + l16;
    #pragma unroll
    for (int mf = 0; mf < 8; ++mf)
        #pragma unroll
        for (int nf = 0; nf < 4; ++nf)
            #pragma unroll
            for (int r = 0; r < 4; ++r)
                epi_store<MODE>(C, Df, Db, N, r0 + mf * 16 + r, c0 + nf * 16, acc[mf][nf][r]);
}

// ---------------------------------------------------------------------------
// 256x128 GEMM (R8 version) — counted-vmcnt, 3 LDS regions x2 buf (96 KiB),
// vmcnt(6). 8 waves (4M x 2N), per-wave 64x64.
// ---------------------------------------------------------------------------
template<int MODE, typename OutT>
__global__ __launch_bounds__(512, 2) void gemm256n128(
    const bf16* __restrict__ A, const bf16* __restrict__ BT,
    const float* __restrict__ Df, const bf16* __restrict__ Db,
    OutT* __restrict__ C, int M, int N, int K)
{
    __shared__ short lds[2][3][128 * 64];   // [buf][A0/A1/B] = 96 KiB

    const int tid = threadIdx.x;
    const int wid = tid >> 6, lane = tid & 63;
    const int wm = wid >> 1, wn = wid & 1;
    const int l16 = lane & 15, hk = lane >> 4;

    const int nwg = gridDim.x * gridDim.y;
    const int orig = blockIdx.y * gridDim.x + blockIdx.x;
    const int q = nwg >> 3, r8 = nwg & 7;
    const int xcd = orig & 7, lid = orig >> 3;
    const int wg = (xcd < r8 ? xcd * (q + 1) : r8 * (q + 1) + (xcd - r8) * q) + lid;
    const int bn = (wg % gridDim.x) * 128;
    const int bm = (wg / gridDim.x) * 256;

    f32x4 acc[4][4] = {};
    const int nt = K >> 6;

    auto stage_half = [&](const bf16* gbase, short* lbase) {
        #pragma unroll
        for (int i = 0; i < 2; ++i) {
            const int ch = i * 512 + tid;
            const int row = ch >> 3, pc = ch & 7;
            const int gc = pc ^ (row & 7);
            const char* src = (const char*)(gbase + (size_t)row * K + gc * 8);
            char* dst = (char*)lbase + (i * 512 + wid * 64) * 16;
            gload16(src, dst);
        }
    };
    auto stage_tile = [&](int t, int buf) {           // 6 loads / thread
        const int k0 = t << 6;
        stage_half(A + (size_t)bm * K + k0,          &lds[buf][0][0]);
        stage_half(A + (size_t)(bm + 128) * K + k0,  &lds[buf][1][0]);
        stage_half(BT + (size_t)bn * K + k0,         &lds[buf][2][0]);
    };

    stage_tile(0, 0);
    stage_tile(1, 1);
    asm volatile("s_waitcnt vmcnt(6)" ::: "memory");
    __builtin_amdgcn_s_barrier();

    int cur = 0;
    for (int t = 0; t < nt; ++t) {
        const short* Ah = &lds[cur][wm >> 1][0];
        const short* Bh = &lds[cur][2][0];
        const int arr = (wm & 1) * 64;
        const int brr = wn * 64;

        short8_t bfr[4][2], afr[2][2];

        #pragma unroll
        for (int ph = 0; ph < 2; ++ph) {
            if (ph == 0) {
                #pragma unroll
                for (int nf = 0; nf < 4; ++nf)
                    #pragma unroll
                    for (int ks = 0; ks < 2; ++ks)
                        bfr[nf][ks] = ldsfrag(Bh, brr + nf * 16 + l16, ks * 4 + hk);
            }
            #pragma unroll
            for (int mi = 0; mi < 2; ++mi)
                #pragma unroll
                for (int ks = 0; ks < 2; ++ks)
                    afr[mi][ks] = ldsfrag(Ah, arr + ph * 32 + mi * 16 + l16, ks * 4 + hk);
            __builtin_amdgcn_s_barrier();
            __builtin_amdgcn_s_setprio(1);
            #pragma unroll
            for (int mi = 0; mi < 2; ++mi)
                #pragma unroll
                for (int nf = 0; nf < 4; ++nf)
                    #pragma unroll
                    for (int ks = 0; ks < 2; ++ks)
                        acc[ph * 2 + mi][nf] = __builtin_amdgcn_mfma_f32_16x16x32_bf16(
                            afr[mi][ks], bfr[nf][ks], acc[ph * 2 + mi][nf], 0, 0, 0);
            __builtin_amdgcn_s_setprio(0);
        }

        __builtin_amdgcn_s_barrier();
        if (t + 2 < nt) {
            stage_tile(t + 2, cur);
            asm volatile("s_waitcnt vmcnt(6)" ::: "memory");
        } else if (t + 1 < nt) {
            asm volatile("s_waitcnt vmcnt(0)" ::: "memory");
        }
        __builtin_amdgcn_s_barrier();
        cur ^= 1;
    }

    const int r0 = bm + wm * 64 + (lane >> 4) * 4;
    const int c0 = bn + wn * 64 + l16;
    #pragma unroll
    for (int mf = 0; mf < 4; ++mf)
        #pragma unroll
        for (int nf = 0; nf < 4; ++nf)
            #pragma unroll
            for (int r = 0; r < 4; ++r)
                epi_store<MODE>(C, Df, Db, N, r0 + mf * 16 + r, c0 + nf * 16, acc[mf][nf][r]);
}

// ---------------------------------------------------------------------------
// Fused gate+up GEMM v2: C = silu(A@BG^T) * (A@BU^T). 256x128 tile.
// EXPERIMENT: m201-style per-phase spread staging at 1-tile depth. Stage
// tile t+1 into the DEAD buffer c^1 (tile t-1's reads completed before the
// boundary barrier): A-halves issued in phase 0, BG/BU in phase 1, all
// aged ~1-2 MFMA phases before the single vmcnt(0)+barrier at the tail.
// 2 barriers/tile (vs 4), no load burst at the boundary.
// ---------------------------------------------------------------------------
__global__ __launch_bounds__(512, 2) void gemm256dual(
    const bf16* __restrict__ A, const bf16* __restrict__ BG,
    const bf16* __restrict__ BU, bf16* __restrict__ C, int M, int N, int K)
{
    __shared__ short lds[2][4][128 * 64];   // [buf][A0/A1/BG/BU] = 128 KiB

    const int tid = threadIdx.x;
    const int wid = tid >> 6, lane = tid & 63;
    const int wm = wid >> 1, wn = wid & 1;
    const int l16 = lane & 15, hk = lane >> 4;

    const int nwg = gridDim.x * gridDim.y;
    const int orig = blockIdx.y * gridDim.x + blockIdx.x;
    const int q = nwg >> 3, r8 = nwg & 7;
    const int xcd = orig & 7, lid = orig >> 3;
    const int wg = (xcd < r8 ? xcd * (q + 1) : r8 * (q + 1) + (xcd - r8) * q) + lid;
    // column-major walk: consecutive wg share the B panels
    const int bm = (wg % gridDim.y) * 256;
    const int bn = (wg / gridDim.y) * 128;

    f32x4 ag[4][4] = {}, au[4][4] = {};
    const int nt = K >> 6;

    auto stage_half = [&](const bf16* gbase, short* lbase) {  // 2 loads/thread
        #pragma unroll
        for (int i = 0; i < 2; ++i) {
            const int ch = i * 512 + tid;
            const int row = ch >> 3, pc = ch & 7;
            const int gc = pc ^ (row & 7);
            const char* src = (const char*)(gbase + (size_t)row * K + gc * 8);
            char* dst = (char*)lbase + (i * 512 + wid * 64) * 16;
            gload16(src, dst);
        }
    };

    // prologue: tile 0 into buf 0, full drain
    stage_half(A + (size_t)bm * K,          &lds[0][0][0]);
    stage_half(A + (size_t)(bm + 128) * K,  &lds[0][1][0]);
    stage_half(BG + (size_t)bn * K,         &lds[0][2][0]);
    stage_half(BU + (size_t)bn * K,         &lds[0][3][0]);
    asm volatile("s_waitcnt vmcnt(0)" ::: "memory");
    __builtin_amdgcn_s_barrier();

    for (int t = 0; t < nt; ++t) {
        const int c = t & 1;
        const short* Ah = &lds[c][wm >> 1][0];
        const short* Gs = &lds[c][2][0];
        const short* Us = &lds[c][3][0];
        const int arr = (wm & 1) * 64;
        const int brr = wn * 64;
        const int k1 = (t + 1) << 6;

        short8_t gfr[4][2], ufr[4][2], afr[2][2];

        // ---- phase 0: reads, then stage A-halves of tile t+1 into c^1 ----
        #pragma unroll
        for (int nf = 0; nf < 4; ++nf)
            #pragma unroll
            for (int ks = 0; ks < 2; ++ks) {
                gfr[nf][ks] = ldsfrag(Gs, brr + nf * 16 + l16, ks * 4 + hk);
                ufr[nf][ks] = ldsfrag(Us, brr + nf * 16 + l16, ks * 4 + hk);
            }
        #pragma unroll
        for (int mi = 0; mi < 2; ++mi)
            #pragma unroll
            for (int ks = 0; ks < 2; ++ks)
                afr[mi][ks] = ldsfrag(Ah, arr + mi * 16 + l16, ks * 4 + hk);
        if (t + 1 < nt) {
            stage_half(A + (size_t)bm * K + k1,         &lds[c ^ 1][0][0]);
            stage_half(A + (size_t)(bm + 128) * K + k1, &lds[c ^ 1][1][0]);
        }
        __builtin_amdgcn_s_setprio(1);
        #pragma unroll
        for (int mi = 0; mi < 2; ++mi)
            #pragma unroll
            for (int nf = 0; nf < 4; ++nf)
                #pragma unroll
                for (int ks = 0; ks < 2; ++ks) {
                    ag[mi][nf] = __builtin_amdgcn_mfma_f32_16x16x32_bf16(
                        afr[mi][ks], gfr[nf][ks], ag[mi][nf], 0, 0, 0);
                    au[mi][nf] = __builtin_amdgcn_mfma_f32_16x16x32_bf16(
                        afr[mi][ks], ufr[nf][ks], au[mi][nf], 0, 0, 0);
                }
        __builtin_amdgcn_s_setprio(0);
        __builtin_amdgcn_s_barrier();   // pacing

        // ---- phase 1: reads, then stage BG/BU of tile t+1 ----
        #pragma unroll
        for (int mi = 0; mi < 2; ++mi)
            #pragma unroll
            for (int ks = 0; ks < 2; ++ks)
                afr[mi][ks] = ldsfrag(Ah, arr + 32 + mi * 16 + l16, ks * 4 + hk);
        if (t + 1 < nt) {
            stage_half(BG + (size_t)bn * K + k1, &lds[c ^ 1][2][0]);
            stage_half(BU + (size_t)bn * K + k1, &lds[c ^ 1][3][0]);
        }
        __builtin_amdgcn_s_setprio(1);
        #pragma unroll
        for (int mi = 0; mi < 2; ++mi)
            #pragma unroll
            for (int nf = 0; nf < 4; ++nf)
                #pragma unroll
                for (int ks = 0; ks < 2; ++ks) {
                    ag[2 + mi][nf] = __builtin_amdgcn_mfma_f32_16x16x32_bf16(
                        afr[mi][ks], gfr[nf][ks], ag[2 + mi][nf], 0, 0, 0);
                    au[2 + mi][nf] = __builtin_amdgcn_mfma_f32_16x16x32_bf16(
                        afr[mi][ks], ufr[nf][ks], au[2 + mi][nf], 0, 0, 0);
                }
        __builtin_amdgcn_s_setprio(0);

        // ---- boundary: drain own aged stages, then sync ----
        asm volatile("s_waitcnt vmcnt(0)" ::: "memory");
        __builtin_amdgcn_s_barrier();
    }

    const int r0 = bm + wm * 64 + (lane >> 4) * 4;
    const int c0 = bn + wn * 64 + l16;
    #pragma unroll
    for (int mf = 0; mf < 4; ++mf)
        #pragma unroll
        for (int nf = 0; nf < 4; ++nf)
            #pragma unroll
            for (int r = 0; r < 4; ++r) {
                const float gg = ag[mf][nf][r];
                const float uu = au[mf][nf][r];
                const float v = gg / (1.f + __expf(-gg)) * uu;
                C[(size_t)(r0 + mf * 16 + r) * N + c0 + nf * 16] = __float2bfloat16(v);
            }
}

// ---------------------------------------------------------------------------
// RoPE: one wave per 64-dim slice. q bf16 (B,S,NH,192), k_pe fp32 in ckv.
// ---------------------------------------------------------------------------
__global__ __launch_bounds__(256) void rope_kernel(
    bf16* __restrict__ q, float* __restrict__ ckv,
    const int* __restrict__ pos_ids,
    const float* __restrict__ sinT, const float* __restrict__ cosT)
{
    const int wid = blockIdx.x * 4 + (threadIdx.x >> 6);
    const int lane = threadIdx.x & 63;
    const int NQ = BS_ * NH_;

    int bs;
    bf16* bptr = nullptr;
    float* fptr = nullptr;
    if (wid < NQ) {
        bs = wid >> 4;
        bptr = q + (size_t)wid * QHD_ + NOPE_;
    } else {
        bs = wid - NQ;
        fptr = ckv + (size_t)bs * CKVP_ + KVL_;
    }
    const int pos = pos_ids[bs];
    const float c  = cosT[pos * ROPE_ + lane];
    const float sn = sinT[pos * ROPE_ + lane];
    const float x = bptr ? __bfloat162float(bptr[lane]) : fptr[lane];
    const int j = lane & 31;
    const float x0 = __shfl(x, 2 * j);
    const float x1 = __shfl(x, 2 * j + 1);
    const float res = (lane < 32) ? fmaf(x0, c, -x1 * sn) : fmaf(x1, c, x0 * sn);
    if (bptr) bptr[lane] = __float2bfloat16(res);
    else      fptr[lane] = res;
}

// ---------------------------------------------------------------------------
// pack_k: Kh (B,NH,S,192) bf16 <- k_nope from KV fp32 + rope'd k_pe from CKV.
// ---------------------------------------------------------------------------
__global__ __launch_bounds__(256) void pack_k(
    const float* __restrict__ KV, const float* __restrict__ CKV,
    bf16* __restrict__ Kh)
{
    const int total = BS_ * NH_ * (QHD_ / 2);
    for (int i = blockIdx.x * 256 + threadIdx.x; i < total; i += gridDim.x * 256) {
        const int d2 = i % (QHD_ / 2);
        const int t  = i / (QHD_ / 2);
        const int s  = t % S_;
        const int hh = (t / S_) % NH_;
        const int bb = t / (S_ * NH_);
        const int d = d2 * 2;
        float2 v;
        if (d < NOPE_) v = *(const float2*)&KV[(((size_t)bb * S_ + s) * NH_ + hh) * KVW_ + d];
        else           v = *(const float2*)&CKV[((size_t)bb * S_ + s) * CKVP_ + KVL_ + (d - NOPE_)];
        union { bf16 h[2]; unsigned int u; } cv;
        cv.h[0] = __float2bfloat16(v.x);
        cv.h[1] = __float2bfloat16(v.y);
        *(unsigned int*)&Kh[((size_t)(bb * NH_ + hh) * S_ + s) * QHD_ + d] = cv.u;
    }
}

// ---------------------------------------------------------------------------
// pack_vt: Vt (B,NH,128,S) bf16 <- V = KV[...,128:256] fp32, transposed.
// ---------------------------------------------------------------------------
__global__ __launch_bounds__(256) void pack_vt(
    const float* __restrict__ KV, bf16* __restrict__ Vt)
{
    __shared__ float t[32][33];
    const int s0 = blockIdx.x * 32, d0 = blockIdx.y * 32;
    const int bh = blockIdx.z;
    const int tx = threadIdx.x & 31, ty = threadIdx.x >> 5;
    for (int r = ty; r < 32; r += 8)
        t[r][tx] = KV[(((size_t)(bh >> 4) * S_ + s0 + r) * NH_ + (bh & 15)) * KVW_ + NOPE_ + d0 + tx];
    __syncthreads();
    for (int r = ty; r < 32; r += 8)
        Vt[((size_t)bh * VHD_ + d0 + r) * S_ + s0 + tx] = __float2bfloat16(t[tx][r]);
}

// ---------------------------------------------------------------------------
// MFMA flash attention v4 — paired blocks (balance) + XCD-chunked heads
// (L2 locality) + no-spill register budget (launch_bounds 512,2).
// ---------------------------------------------------------------------------
__global__ __launch_bounds__(512, 2) void attn_mfma(
    const bf16* __restrict__ Qp, const bf16* __restrict__ Kh,
    const bf16* __restrict__ Vt, bf16* __restrict__ outp)
{
    __shared__ __align__(16) short Ks[64][192];    // 24 chunks/row, XOR-swizzled
    __shared__ __align__(16) short Vs[128][64];    // 8 chunks/row, XOR-swizzled
    __shared__ __align__(16) short Ps[8][16][64];  // per-wave, XOR-swizzled

    const int tid = threadIdx.x;
    const int wid = tid >> 6, lane = tid & 63;
    const int l16 = lane & 15;
    const int hk  = lane >> 4;          // 0..3
    const int lk  = hk << 3;
    const int pr  = hk << 2;
    const int lx  = l16 & 7;

    const int bid = blockIdx.x;
    const int orig = (bid & 7) * 64 + (bid >> 3);
    const int j  = orig & 15;           // pair index
    const int gh = orig >> 4;           // 0..31
    const int h = gh & 15, b = gh >> 4;

    const int setB = wid >> 2;
    const int qblk = setB ? (31 - j) : j;
    const int qw = qblk * 64 + (wid & 3) * 16;
    const int myNt = qblk + 1;
    const int ntStage = 32 - j;

    short8_t qf[6];
    const bf16* qbase = Qp + (((size_t)b * S_ + qw + l16) * NH_ + h) * QHD_;
    #pragma unroll
    for (int kk = 0; kk < 6; ++kk)
        qf[kk] = *(const short8_t*)(qbase + kk * 32 + lk);

    const bf16* Khb = Kh + (size_t)(b * NH_ + h) * S_ * QHD_;
    const bf16* Vtb = Vt + (size_t)(b * NH_ + h) * VHD_ * S_;

    f32x4 o[8] = {};
    float mr[4] = {-3.0e38f, -3.0e38f, -3.0e38f, -3.0e38f};
    float lr[4] = {0.f, 0.f, 0.f, 0.f};
    const float scale = 0.07216878364870323f;  // 192^-0.5

    const int krow = tid >> 3, kc0 = (tid & 7) * 3;
    const int vrow = tid >> 2, vc0 = (tid & 3) * 2;

    short8_t kreg[3], vreg[2];
    auto load_tile = [&](int kt) {
        const short* ksrc = (const short*)(Khb + ((size_t)(kt * 64 + krow)) * QHD_);
        kreg[0] = *(const short8_t*)(ksrc + (kc0 + 0) * 8);
        kreg[1] = *(const short8_t*)(ksrc + (kc0 + 1) * 8);
        kreg[2] = *(const short8_t*)(ksrc + (kc0 + 2) * 8);
        const short* vsrc = (const short*)(Vtb + (size_t)vrow * S_ + kt * 64);
        vreg[0] = *(const short8_t*)(vsrc + (vc0 + 0) * 8);
        vreg[1] = *(const short8_t*)(vsrc + (vc0 + 1) * 8);
    };
    auto write_tile = [&]() {
        const int kx = krow & 7, vx = vrow & 7;
        *(short8_t*)&Ks[krow][((kc0 + 0) ^ kx) << 3] = kreg[0];
        *(short8_t*)&Ks[krow][((kc0 + 1) ^ kx) << 3] = kreg[1];
        *(short8_t*)&Ks[krow][((kc0 + 2) ^ kx) << 3] = kreg[2];
        *(short8_t*)&Vs[vrow][((vc0 + 0) ^ vx) << 3] = vreg[0];
        *(short8_t*)&Vs[vrow][((vc0 + 1) ^ vx) << 3] = vreg[1];
    };

    load_tile(0);

    for (int t = 0; t < ntStage; ++t) {
        write_tile();
        __syncthreads();
        if (t + 1 < ntStage) load_tile(t + 1);
        if (t < myNt) {
            const int k0 = t << 6;
            f32x4 s[4] = {};
            #pragma unroll
            for (int kk = 0; kk < 6; ++kk) {
                #pragma unroll
                for (int n = 0; n < 4; ++n) {
                    short8_t kf = *(const short8_t*)&Ks[n * 16 + l16][((kk * 4 + hk) ^ lx) << 3];
                    s[n] = __builtin_amdgcn_mfma_f32_16x16x32_bf16(qf[kk], kf, s[n], 0, 0, 0);
                }
            }
            if (t == myNt - 1) {
                #pragma unroll
                for (int n = 0; n < 4; ++n) {
                    const int kg = k0 + n * 16 + l16;
                    #pragma unroll
                    for (int r = 0; r < 4; ++r) {
                        if (kg > qw + pr + r) s[n][r] = -3.0e38f;
                    }
                }
            }
            #pragma unroll
            for (int r = 0; r < 4; ++r) {
                float rm = fmaxf(fmaxf(s[0][r], s[1][r]), fmaxf(s[2][r], s[3][r]));
                rm = fmaxf(rm, __shfl_xor(rm, 1));
                rm = fmaxf(rm, __shfl_xor(rm, 2));
                rm = fmaxf(rm, __shfl_xor(rm, 4));
                rm = fmaxf(rm, __shfl_xor(rm, 8));
                const float mnew = fmaxf(mr[r], rm);
                const float corr = __expf((mr[r] - mnew) * scale);
                mr[r] = mnew;
                float rs = 0.f;
                #pragma unroll
                for (int n = 0; n < 4; ++n) {
                    const float p = __expf((s[n][r] - mnew) * scale);
                    s[n][r] = p;
                    rs += p;
                }
                rs += __shfl_xor(rs, 1);
                rs += __shfl_xor(rs, 2);
                rs += __shfl_xor(rs, 4);
                rs += __shfl_xor(rs, 8);
                lr[r] = lr[r] * corr + rs;
                #pragma unroll
                for (int n = 0; n < 8; ++n) o[n][r] *= corr;
            }
            #pragma unroll
            for (int n = 0; n < 4; ++n) {
                #pragma unroll
                for (int r = 0; r < 4; ++r) {
                    union { bf16 hh; short u; } cv;
                    cv.hh = __float2bfloat16(s[n][r]);
                    const int row = pr + r;
                    const int col = (((n * 2 + (l16 >> 3)) ^ (row & 7)) << 3) + (l16 & 7);
                    Ps[wid][row][col] = cv.u;
                }
            }
            #pragma unroll
            for (int kk2 = 0; kk2 < 2; ++kk2) {
                short8_t pf = *(const short8_t*)&Ps[wid][l16][((kk2 * 4 + hk) ^ lx) << 3];
                #pragma unroll
                for (int n = 0; n < 8; ++n) {
                    short8_t vf = *(const short8_t*)&Vs[n * 16 + l16][((kk2 * 4 + hk) ^ lx) << 3];
                    o[n] = __builtin_amdgcn_mfma_f32_16x16x32_bf16(pf, vf, o[n], 0, 0, 0);
                }
            }
        }
        __syncthreads();
    }

    float inv[4];
    #pragma unroll
    for (int r = 0; r < 4; ++r) inv[r] = 1.f / lr[r];
    bf16* ob = outp + (((size_t)b * S_ + qw + pr) * NH_ + h) * VHD_;
    #pragma unroll
    for (int r = 0; r < 4; ++r)
        #pragma unroll
        for (int n = 0; n < 8; ++n)
            ob[(size_t)r * (NH_ * VHD_) + n * 16 + l16] = __float2bfloat16(o[n][r] * inv[r]);
}

// ---------------------------------------------------------------------------
// Launch (R8 configuration)
// ---------------------------------------------------------------------------
extern "C" void kernel_launch(void* const* d_in, const int* in_sizes, int n_in,
                              void* d_out, int out_size, void* d_ws, size_t ws_size,
                              hipStream_t stream)
{
    const float* hidden  = (const float*)d_in[0];
    const float* ln1_w   = (const float*)d_in[1];
    const float* q_a_k   = (const float*)d_in[2];
    const float* q_a_ln  = (const float*)d_in[3];
    const float* q_b_k   = (const float*)d_in[4];
    const float* kv_a_k  = (const float*)d_in[5];
    const float* kv_a_ln = (const float*)d_in[6];
    const float* kv_b_k  = (const float*)d_in[7];
    const float* o_k     = (const float*)d_in[8];
    const float* ln2_w   = (const float*)d_in[9];
    const float* gate_k  = (const float*)d_in[10];
    const float* up_k    = (const float*)d_in[11];
    const float* down_k  = (const float*)d_in[12];
    const float* sinT    = (const float*)d_in[13];
    const float* cosT    = (const float*)d_in[14];
    const int*   pos     = (const int*)d_in[15];
    float* out = (float*)d_out;
    char* ws = (char*)d_ws;

    // ---- Phase-1 workspace layout ----
    bf16* qaT   = (bf16*)(ws + 0);            // [1536][2048]  6,291,456
    bf16* qbT   = (bf16*)(ws + 6291456);      // [3072][1536]  9,437,184
    bf16* kvaT  = (bf16*)(ws + 15728640);     // [640][2048]   2,621,440
    bf16* kvbT  = (bf16*)(ws + 18350080);     // [4096][512]   4,194,304
    bf16* oT    = (bf16*)(ws + 22544384);     // [2048][2048]  8,388,608
    bf16* Xb    = (bf16*)(ws + 30932992);     // [4096][2048] 16,777,216
    bf16* QAb   = (bf16*)(ws + 47710208);     // [4096][1536] 12,582,912
    bf16* CKVNb = (bf16*)(ws + 60293120);     // [4096][512]   4,194,304
    bf16* Qb    = (bf16*)(ws + 64487424);     // [4096][3072] 25,165,824
    float* CKV  = (float*)(ws + 89653248);    // [4096][640]  10,485,760
    float* KV   = (float*)(ws + 100139008);   // [4096][4096] 67,108,864
    bf16* ATTNb = (bf16*)(ws + 167247872);    // [4096][2048] 16,777,216
    bf16* Vt    = (bf16*)(ws + 0);            // overlays dead qaT/qbT/kvaT
    bf16* Kh    = (bf16*)(ws + 30932992);     // overlays dead Xb+QAb
    // ---- Phase-2 layout ----
    bf16* gateT = (bf16*)(ws + 0);            // [8192][2048] 33,554,432
    bf16* upT   = (bf16*)(ws + 33554432);     // [8192][2048] 33,554,432
    bf16* downT = (bf16*)(ws + 67108864);     // [2048][8192] 33,554,432
    bf16* X2b   = (bf16*)(ws + 100663296);    // [4096][2048] 16,777,216
    bf16* MLPb  = (bf16*)(ws + 117440512);    // [4096][8192] 67,108,864

    const dim3 tb(32, 8);

    // 0. weight transposes (attention-phase weights)
    transp_bf16<<<dim3(1536 / 32, 2048 / 32), tb, 0, stream>>>(q_a_k, qaT, 2048, 1536, 1536);
    transp_bf16<<<dim3(3072 / 32, 1536 / 32), tb, 0, stream>>>(q_b_k, qbT, 1536, 3072, 3072);
    transp_bf16<<<dim3(640 / 32, 2048 / 32), tb, 0, stream>>>(kv_a_k, kvaT, 2048, 576, 640);
    transp_bf16<<<dim3(4096 / 32, 512 / 32), tb, 0, stream>>>(kv_b_k, kvbT, 512, 4096, 4096);
    transp_bf16<<<dim3(2048 / 32, 2048 / 32), tb, 0, stream>>>(o_k, oT, 2048, 2048, 2048);

    // 1. Xb = rmsnorm(hidden)
    rmsnorm2<float, bf16><<<BS_, 256, 0, stream>>>(hidden, ln1_w, Xb, H_, H_, H_);
    // 2. QAb = Xb @ qaT   (128-tile)
    gemm_bf16<0, bf16><<<dim3(QL_ / 128, BS_ / 128), 256, 0, stream>>>(
        Xb, qaT, nullptr, nullptr, QAb, BS_, QL_, H_);
    // 3. QAb = rmsnorm(QAb) in place
    rmsnorm2<bf16, bf16><<<BS_, 256, 0, stream>>>(QAb, q_a_ln, QAb, QL_, QL_, QL_);
    // 4. Qb = QAb @ qbT   (256x128-tile, grid 24x16)
    gemm256n128<0, bf16><<<dim3((NH_ * QHD_) / 128, BS_ / 256), 512, 0, stream>>>(
        QAb, qbT, nullptr, nullptr, Qb, BS_, NH_ * QHD_, QL_);
    // 5. CKV = Xb @ kvaT (fp32, padded width 640; 128-tile)
    gemm_bf16<0, float><<<dim3(CKVP_ / 128, BS_ / 128), 256, 0, stream>>>(
        Xb, kvaT, nullptr, nullptr, CKV, BS_, CKVP_, H_);
    // 6. CKVNb = rmsnorm(CKV[:, :512])
    rmsnorm2<float, bf16><<<BS_, 256, 0, stream>>>(CKV, kv_a_ln, CKVNb, KVL_, CKVP_, KVL_);
    // 7. KV = CKVNb @ kvbT (fp32, 256-tile)
    gemm256<0, float><<<dim3((NH_ * KVW_) / 256, BS_ / 256), 512, 0, stream>>>(
        CKVNb, kvbT, nullptr, nullptr, KV, BS_, NH_ * KVW_, KVL_);
    // 8. RoPE in place on Qb and CKV k_pe
    rope_kernel<<<(BS_ * NH_ + BS_) / 4, 256, 0, stream>>>(Qb, CKV, pos, sinT, cosT);
    // 9. pack K and V^T into head-major bf16
    pack_k<<<2048, 256, 0, stream>>>(KV, CKV, Kh);
    pack_vt<<<dim3(S_ / 32, VHD_ / 32, B_ * NH_), 256, 0, stream>>>(KV, Vt);
    // 10. MFMA flash attention -> ATTNb
    attn_mfma<<<dim3(512), 512, 0, stream>>>(Qb, Kh, Vt, ATTNb);
    // 11. d_out = ATTNb @ oT + hidden (fp32, 256x128-tile)
    gemm256n128<1, float><<<dim3(H_ / 128, BS_ / 256), 512, 0, stream>>>(
        ATTNb, oT, hidden, nullptr, out, BS_, H_, NH_ * VHD_);

    // 12. MLP-phase weight transposes
    transp_bf16<<<dim3(8192 / 32, 2048 / 32), tb, 0, stream>>>(gate_k, gateT, 2048, 8192, 8192);
    transp_bf16<<<dim3(8192 / 32, 2048 / 32), tb, 0, stream>>>(up_k, upT, 2048, 8192, 8192);
    transp_bf16<<<dim3(2048 / 32, 8192 / 32), tb, 0, stream>>>(down_k, downT, 8192, 2048, 2048);

    // 13. X2b = rmsnorm(d_out)
    rmsnorm2<float, bf16><<<BS_, 256, 0, stream>>>(out, ln2_w, X2b, H_, H_, H_);
    // 14. MLPb = silu(X2b @ gateT) * (X2b @ upT)  — fused dual GEMM (v2)
    gemm256dual<<<dim3(FF_ / 128, BS_ / 256), 512, 0, stream>>>(
        X2b, gateT, upT, MLPb, BS_, FF_, H_);
    // 15. d_out = MLPb @ downT + d_out (256x128-tile)
    gemm256n128<1, float><<<dim3(H_ / 128, BS_ / 256), 512, 0, stream>>>(
        MLPb, downT, out, nullptr, out, BS_, H_, FF_);
}

// Round 12
// 928.635 us; speedup vs baseline: 1.1682x; 1.0535x over previous
//
#include <hip/hip_runtime.h>
#include <hip/hip_bf16.h>
#include <cstdint>

#define B_ 2
#define S_ 2048
#define H_ 2048
#define NH_ 16
#define QL_ 1536
#define KVL_ 512
#define NOPE_ 128
#define ROPE_ 64
#define QHD_ 192
#define VHD_ 128
#define FF_ 8192
#define BS_ (B_ * S_)            // 4096 rows
#define CKVP_ 640                // padded ckv width (576 -> 640 for N%128==0)
#define KVW_ (NOPE_ + VHD_)      // 256 per head

typedef __hip_bfloat16 bf16;
typedef __attribute__((ext_vector_type(8))) short short8_t;  // 8 bf16 (4 VGPRs)
typedef __attribute__((ext_vector_type(4))) float f32x4;

__device__ __forceinline__ float ldf(const float* p, size_t i) { return p[i]; }
__device__ __forceinline__ float ldf(const bf16* p, size_t i) { return __bfloat162float(p[i]); }
__device__ __forceinline__ void stf(float* p, size_t i, float v) { p[i] = v; }
__device__ __forceinline__ void stf(bf16* p, size_t i, float v) { p[i] = __float2bfloat16(v); }

__device__ __forceinline__ void gload16(const void* g, void* l)
{
    __builtin_amdgcn_global_load_lds((const unsigned int*)g, (unsigned int*)l, 16, 0, 0);
}

// ---------------------------------------------------------------------------
// Transpose + convert: in fp32 [K][N] -> out bf16 [Npad][K]; rows n>=N zeroed.
// ---------------------------------------------------------------------------
__global__ __launch_bounds__(256) void transp_bf16(
    const float* __restrict__ in, bf16* __restrict__ out, int K, int N, int Npad)
{
    __shared__ float t[32][33];
    const int n0 = blockIdx.x * 32, k0 = blockIdx.y * 32;
    for (int r = threadIdx.y; r < 32; r += 8) {
        const int n = n0 + threadIdx.x;
        t[r][threadIdx.x] = (n < N) ? in[(size_t)(k0 + r) * N + n] : 0.f;
    }
    __syncthreads();
    for (int r = threadIdx.y; r < 32; r += 8) {
        out[(size_t)(n0 + r) * K + k0 + threadIdx.x] = __float2bfloat16(t[threadIdx.x][r]);
    }
}

// ---------------------------------------------------------------------------
// RMSNorm (templated dtypes): one 256-thread block per row.
// ---------------------------------------------------------------------------
template<typename InT, typename OutT>
__global__ __launch_bounds__(256) void rmsnorm2(
    const InT* __restrict__ in, const float* __restrict__ w,
    OutT* __restrict__ out, int cols, int istride, int ostride)
{
    const int row = blockIdx.x;
    const InT* ip = in + (size_t)row * istride;
    OutT* op = out + (size_t)row * ostride;

    float ss = 0.f;
    for (int c = threadIdx.x; c < cols; c += 256) {
        float v = ldf(ip, c);
        ss = fmaf(v, v, ss);
    }
    #pragma unroll
    for (int off = 32; off; off >>= 1) ss += __shfl_xor(ss, off);
    __shared__ float red[4];
    if ((threadIdx.x & 63) == 0) red[threadIdx.x >> 6] = ss;
    __syncthreads();
    const float total = red[0] + red[1] + red[2] + red[3];
    const float scale = rsqrtf(total / (float)cols + 1e-6f);
    for (int c = threadIdx.x; c < cols; c += 256) {
        stf(op, c, ldf(ip, c) * scale * w[c]);
    }
}

// ---------------------------------------------------------------------------
// 128x128 2-phase GEMM (m97 structure) — used for kva (N=640).
// ---------------------------------------------------------------------------
template<int MODE, typename OutT>
__global__ __launch_bounds__(256) void gemm_bf16(
    const bf16* __restrict__ A, const bf16* __restrict__ BT,
    const float* __restrict__ Df, const bf16* __restrict__ Db,
    OutT* __restrict__ C, int M, int N, int K)
{
    __shared__ short As[128 * 32];
    __shared__ short Bs[128 * 32];
    const int tid = threadIdx.x;
    const int wid = tid >> 6, lane = tid & 63;
    const int bm = blockIdx.y * 128, bn = blockIdx.x * 128;
    const int wr = (wid >> 1) * 64, wc = (wid & 1) * 64;
    const int l16 = lane & 15;
    const int lk = (lane >> 4) << 3;

    f32x4 acc[4][4] = {};

    for (int k0 = 0; k0 < K; k0 += 32) {
        #pragma unroll
        for (int is = 0; is < 2; ++is) {
            const int c = is * 256 + tid;
            const int row = c >> 2;
            const int cb = (c & 3) * 16;
            const char* srcA = (const char*)A + ((size_t)(bm + row) * K + k0) * 2 + cb;
            const char* srcB = (const char*)BT + ((size_t)(bn + row) * K + k0) * 2 + cb;
            char* dstA = (char*)As + (is * 256 + wid * 64) * 16;
            char* dstB = (char*)Bs + (is * 256 + wid * 64) * 16;
            gload16(srcA, dstA);
            gload16(srcB, dstB);
        }
        __syncthreads();

        short8_t a[4], b[4];
        const short* ApW = As + (wr + l16) * 32 + lk;
        const short* BpW = Bs + (wc + l16) * 32 + lk;
        #pragma unroll
        for (int m = 0; m < 4; ++m) a[m] = *(const short8_t*)(ApW + m * 16 * 32);
        #pragma unroll
        for (int n = 0; n < 4; ++n) b[n] = *(const short8_t*)(BpW + n * 16 * 32);
        #pragma unroll
        for (int m = 0; m < 4; ++m)
            #pragma unroll
            for (int n = 0; n < 4; ++n)
                acc[m][n] = __builtin_amdgcn_mfma_f32_16x16x32_bf16(a[m], b[n], acc[m][n], 0, 0, 0);
        __syncthreads();
    }

    const int r0 = bm + wr + ((lane >> 4) << 2);
    const int c0 = bn + wc + l16;
    #pragma unroll
    for (int m = 0; m < 4; ++m) {
        #pragma unroll
        for (int n = 0; n < 4; ++n) {
            const int row = r0 + m * 16;
            const int col = c0 + n * 16;
            #pragma unroll
            for (int r = 0; r < 4; ++r) {
                const size_t off = (size_t)(row + r) * N + col;
                float v = acc[m][n][r];
                if (MODE == 1) v += Df[off];
                stf(C, off, v);
            }
        }
    }
}

// ---------------------------------------------------------------------------
// Epilogue helper shared by the big GEMMs.
// ---------------------------------------------------------------------------
template<int MODE, typename OutT>
__device__ __forceinline__ void epi_store(
    OutT* __restrict__ C, const float* __restrict__ Df, const bf16* __restrict__ Db,
    int N, int row, int col, float v)
{
    const size_t off = (size_t)row * N + col;
    if (MODE == 1) v += Df[off];
    if (MODE == 2) {
        const float g = __bfloat162float(Db[off]);
        v *= g / (1.f + __expf(-g));
    }
    stf(C, off, v);
}

__device__ __forceinline__ short8_t ldsfrag(const short* half_base, int r, int c)
{
    return *(const short8_t*)(half_base + r * 64 + ((c ^ (r & 7)) << 3));
}

// ---------------------------------------------------------------------------
// 256x256 GEMM v2: spread-stage schedule (dual-v2 pattern). 4 phases/tile,
// stage tile t+1 into dead buffer (A halves in ph0/ph1, B halves in ph2/ph3
// front-loaded as A0,A1 in ph0 / B0,B1 in ph1 for aging), 4 barriers/tile,
// single vmcnt(0) on aged loads at tail. MODE 3: kvb fused epilogue —
// d<128 cols -> Kh bf16 head-major; d>=128 -> fp32 C (v part for pack_vt).
// ---------------------------------------------------------------------------
template<int MODE, typename OutT>
__global__ __launch_bounds__(512, 2) void gemm256(
    const bf16* __restrict__ A, const bf16* __restrict__ BT,
    const float* __restrict__ Df, const bf16* __restrict__ Db,
    OutT* __restrict__ C, bf16* __restrict__ KhO, int M, int N, int K)
{
    __shared__ short lds[2][2][2][128 * 64];   // [buf][A/B][half] = 128 KiB

    const int tid = threadIdx.x;
    const int wid = tid >> 6, lane = tid & 63;
    const int wm = wid >> 2, wn = wid & 3;
    const int l16 = lane & 15, hk = lane >> 4;

    const int nwg = gridDim.x * gridDim.y;
    const int orig = blockIdx.y * gridDim.x + blockIdx.x;
    const int q = nwg >> 3, r8 = nwg & 7;
    const int xcd = orig & 7, lid = orig >> 3;
    const int wg = (xcd < r8 ? xcd * (q + 1) : r8 * (q + 1) + (xcd - r8) * q) + lid;
    const int bn = (wg % gridDim.x) * 256;
    const int bm = (wg / gridDim.x) * 256;

    f32x4 acc[8][4] = {};
    const int nt = K >> 6;

    auto stage_half = [&](const bf16* gbase, short* lbase) {
        #pragma unroll
        for (int i = 0; i < 2; ++i) {
            const int ch = i * 512 + tid;
            const int row = ch >> 3, pc = ch & 7;
            const int gc = pc ^ (row & 7);
            const char* src = (const char*)(gbase + (size_t)row * K + gc * 8);
            char* dst = (char*)lbase + (i * 512 + wid * 64) * 16;
            gload16(src, dst);
        }
    };

    // prologue: tile 0 into buf 0
    stage_half(A + (size_t)bm * K,          &lds[0][0][0][0]);
    stage_half(A + (size_t)(bm + 128) * K,  &lds[0][0][1][0]);
    stage_half(BT + (size_t)bn * K,         &lds[0][1][0][0]);
    stage_half(BT + (size_t)(bn + 128) * K, &lds[0][1][1][0]);
    asm volatile("s_waitcnt vmcnt(0)" ::: "memory");
    __builtin_amdgcn_s_barrier();

    for (int t = 0; t < nt; ++t) {
        const int c = t & 1;
        const short* Ah = &lds[c][0][wm][0];
        const short* Bh = &lds[c][1][wn >> 1][0];
        const int brr = (wn & 1) * 64;
        const int k1 = (t + 1) << 6;
        const bool pf = (t + 1 < nt);

        short8_t bfr[4][2], afr[2][2];

        #pragma unroll
        for (int ph = 0; ph < 4; ++ph) {
            if (ph == 0) {
                #pragma unroll
                for (int nf = 0; nf < 4; ++nf)
                    #pragma unroll
                    for (int ks = 0; ks < 2; ++ks)
                        bfr[nf][ks] = ldsfrag(Bh, brr + nf * 16 + l16, ks * 4 + hk);
            }
            #pragma unroll
            for (int mi = 0; mi < 2; ++mi)
                #pragma unroll
                for (int ks = 0; ks < 2; ++ks)
                    afr[mi][ks] = ldsfrag(Ah, ph * 32 + mi * 16 + l16, ks * 4 + hk);
            if (pf) {
                if (ph == 0) {
                    stage_half(A + (size_t)bm * K + k1,          &lds[c ^ 1][0][0][0]);
                    stage_half(A + (size_t)(bm + 128) * K + k1,  &lds[c ^ 1][0][1][0]);
                } else if (ph == 1) {
                    stage_half(BT + (size_t)bn * K + k1,         &lds[c ^ 1][1][0][0]);
                    stage_half(BT + (size_t)(bn + 128) * K + k1, &lds[c ^ 1][1][1][0]);
                }
            }
            __builtin_amdgcn_s_setprio(1);
            #pragma unroll
            for (int mi = 0; mi < 2; ++mi)
                #pragma unroll
                for (int nf = 0; nf < 4; ++nf)
                    #pragma unroll
                    for (int ks = 0; ks < 2; ++ks)
                        acc[ph * 2 + mi][nf] = __builtin_amdgcn_mfma_f32_16x16x32_bf16(
                            afr[mi][ks], bfr[nf][ks], acc[ph * 2 + mi][nf], 0, 0, 0);
            __builtin_amdgcn_s_setprio(0);
            if (ph == 3) asm volatile("s_waitcnt vmcnt(0)" ::: "memory");
            __builtin_amdgcn_s_barrier();
        }
    }

    const int r0 = bm + wm * 128 + (lane >> 4) * 4;
    const int c0 = bn + wn * 64 + l16;
    #pragma unroll
    for (int mf = 0; mf < 8; ++mf)
        #pragma unroll
        for (int nf = 0; nf < 4; ++nf)
            #pragma unroll
            for (int r = 0; r < 4; ++r) {
                const int row = r0 + mf * 16 + r;
                const int col = c0 + nf * 16;
                float v = acc[mf][nf][r];
                if (MODE == 3) {
                    const int d = col & 255;
                    if (d < NOPE_) {
                        const int hh = col >> 8;
                        const int bb = row >> 11, s = row & 2047;
                        KhO[((size_t)(bb * NH_ + hh) * S_ + s) * QHD_ + d] = __float2bfloat16(v);
                    } else {
                        C[(size_t)row * N + col] = v;
                    }
                } else {
                    epi_store<MODE>(C, Df, Db, N, row, col, v);
                }
            }
}

// ---------------------------------------------------------------------------
// 256x128 GEMM v2 — spread-stage schedule. 2 phases/tile, stage A in ph0,
// B in ph1, 2 barriers/tile, single vmcnt(0) at tail. 8 waves (4M x 2N).
// ---------------------------------------------------------------------------
template<int MODE, typename OutT>
__global__ __launch_bounds__(512, 2) void gemm256n128(
    const bf16* __restrict__ A, const bf16* __restrict__ BT,
    const float* __restrict__ Df, const bf16* __restrict__ Db,
    OutT* __restrict__ C, int M, int N, int K)
{
    __shared__ short lds[2][3][128 * 64];   // [buf][A0/A1/B] = 96 KiB

    const int tid = threadIdx.x;
    const int wid = tid >> 6, lane = tid & 63;
    const int wm = wid >> 1, wn = wid & 1;
    const int l16 = lane & 15, hk = lane >> 4;

    const int nwg = gridDim.x * gridDim.y;
    const int orig = blockIdx.y * gridDim.x + blockIdx.x;
    const int q = nwg >> 3, r8 = nwg & 7;
    const int xcd = orig & 7, lid = orig >> 3;
    const int wg = (xcd < r8 ? xcd * (q + 1) : r8 * (q + 1) + (xcd - r8) * q) + lid;
    const int bn = (wg % gridDim.x) * 128;
    const int bm = (wg / gridDim.x) * 256;

    f32x4 acc[4][4] = {};
    const int nt = K >> 6;

    auto stage_half = [&](const bf16* gbase, short* lbase) {
        #pragma unroll
        for (int i = 0; i < 2; ++i) {
            const int ch = i * 512 + tid;
            const int row = ch >> 3, pc = ch & 7;
            const int gc = pc ^ (row & 7);
            const char* src = (const char*)(gbase + (size_t)row * K + gc * 8);
            char* dst = (char*)lbase + (i * 512 + wid * 64) * 16;
            gload16(src, dst);
        }
    };

    stage_half(A + (size_t)bm * K,          &lds[0][0][0]);
    stage_half(A + (size_t)(bm + 128) * K,  &lds[0][1][0]);
    stage_half(BT + (size_t)bn * K,         &lds[0][2][0]);
    asm volatile("s_waitcnt vmcnt(0)" ::: "memory");
    __builtin_amdgcn_s_barrier();

    for (int t = 0; t < nt; ++t) {
        const int c = t & 1;
        const short* Ah = &lds[c][wm >> 1][0];
        const short* Bh = &lds[c][2][0];
        const int arr = (wm & 1) * 64;
        const int brr = wn * 64;
        const int k1 = (t + 1) << 6;
        const bool pf = (t + 1 < nt);

        short8_t bfr[4][2], afr[2][2];

        // ---- phase 0 ----
        #pragma unroll
        for (int nf = 0; nf < 4; ++nf)
            #pragma unroll
            for (int ks = 0; ks < 2; ++ks)
                bfr[nf][ks] = ldsfrag(Bh, brr + nf * 16 + l16, ks * 4 + hk);
        #pragma unroll
        for (int mi = 0; mi < 2; ++mi)
            #pragma unroll
            for (int ks = 0; ks < 2; ++ks)
                afr[mi][ks] = ldsfrag(Ah, arr + mi * 16 + l16, ks * 4 + hk);
        if (pf) {
            stage_half(A + (size_t)bm * K + k1,         &lds[c ^ 1][0][0]);
            stage_half(A + (size_t)(bm + 128) * K + k1, &lds[c ^ 1][1][0]);
        }
        __builtin_amdgcn_s_setprio(1);
        #pragma unroll
        for (int mi = 0; mi < 2; ++mi)
            #pragma unroll
            for (int nf = 0; nf < 4; ++nf)
                #pragma unroll
                for (int ks = 0; ks < 2; ++ks)
                    acc[mi][nf] = __builtin_amdgcn_mfma_f32_16x16x32_bf16(
                        afr[mi][ks], bfr[nf][ks], acc[mi][nf], 0, 0, 0);
        __builtin_amdgcn_s_setprio(0);
        __builtin_amdgcn_s_barrier();   // pacing

        // ---- phase 1 ----
        #pragma unroll
        for (int mi = 0; mi < 2; ++mi)
            #pragma unroll
            for (int ks = 0; ks < 2; ++ks)
                afr[mi][ks] = ldsfrag(Ah, arr + 32 + mi * 16 + l16, ks * 4 + hk);
        if (pf) stage_half(BT + (size_t)bn * K + k1, &lds[c ^ 1][2][0]);
        __builtin_amdgcn_s_setprio(1);
        #pragma unroll
        for (int mi = 0; mi < 2; ++mi)
            #pragma unroll
            for (int nf = 0; nf < 4; ++nf)
                #pragma unroll
                for (int ks = 0; ks < 2; ++ks)
                    acc[2 + mi][nf] = __builtin_amdgcn_mfma_f32_16x16x32_bf16(
                        afr[mi][ks], bfr[nf][ks], acc[2 + mi][nf], 0, 0, 0);
        __builtin_amdgcn_s_setprio(0);
        asm volatile("s_waitcnt vmcnt(0)" ::: "memory");
        __builtin_amdgcn_s_barrier();   // tail
    }

    const int r0 = bm + wm * 64 + (lane >> 4) * 4;
    const int c0 = bn + wn * 64 + l16;
    #pragma unroll
    for (int mf = 0; mf < 4; ++mf)
        #pragma unroll
        for (int nf = 0; nf < 4; ++nf)
            #pragma unroll
            for (int r = 0; r < 4; ++r)
                epi_store<MODE>(C, Df, Db, N, r0 + mf * 16 + r, c0 + nf * 16, acc[mf][nf][r]);
}

// ---------------------------------------------------------------------------
// Fused gate+up GEMM v2 (proven R10): C = silu(A@BG^T) * (A@BU^T).
// ---------------------------------------------------------------------------
__global__ __launch_bounds__(512, 2) void gemm256dual(
    const bf16* __restrict__ A, const bf16* __restrict__ BG,
    const bf16* __restrict__ BU, bf16* __restrict__ C, int M, int N, int K)
{
    __shared__ short lds[2][4][128 * 64];   // [buf][A0/A1/BG/BU] = 128 KiB

    const int tid = threadIdx.x;
    const int wid = tid >> 6, lane = tid & 63;
    const int wm = wid >> 1, wn = wid & 1;
    const int l16 = lane & 15, hk = lane >> 4;

    const int nwg = gridDim.x * gridDim.y;
    const int orig = blockIdx.y * gridDim.x + blockIdx.x;
    const int q = nwg >> 3, r8 = nwg & 7;
    const int xcd = orig & 7, lid = orig >> 3;
    const int wg = (xcd < r8 ? xcd * (q + 1) : r8 * (q + 1) + (xcd - r8) * q) + lid;
    const int bm = (wg % gridDim.y) * 256;
    const int bn = (wg / gridDim.y) * 128;

    f32x4 ag[4][4] = {}, au[4][4] = {};
    const int nt = K >> 6;

    auto stage_half = [&](const bf16* gbase, short* lbase) {
        #pragma unroll
        for (int i = 0; i < 2; ++i) {
            const int ch = i * 512 + tid;
            const int row = ch >> 3, pc = ch & 7;
            const int gc = pc ^ (row & 7);
            const char* src = (const char*)(gbase + (size_t)row * K + gc * 8);
            char* dst = (char*)lbase + (i * 512 + wid * 64) * 16;
            gload16(src, dst);
        }
    };

    stage_half(A + (size_t)bm * K,          &lds[0][0][0]);
    stage_half(A + (size_t)(bm + 128) * K,  &lds[0][1][0]);
    stage_half(BG + (size_t)bn * K,         &lds[0][2][0]);
    stage_half(BU + (size_t)bn * K,         &lds[0][3][0]);
    asm volatile("s_waitcnt vmcnt(0)" ::: "memory");
    __builtin_amdgcn_s_barrier();

    for (int t = 0; t < nt; ++t) {
        const int c = t & 1;
        const short* Ah = &lds[c][wm >> 1][0];
        const short* Gs = &lds[c][2][0];
        const short* Us = &lds[c][3][0];
        const int arr = (wm & 1) * 64;
        const int brr = wn * 64;
        const int k1 = (t + 1) << 6;

        short8_t gfr[4][2], ufr[4][2], afr[2][2];

        #pragma unroll
        for (int nf = 0; nf < 4; ++nf)
            #pragma unroll
            for (int ks = 0; ks < 2; ++ks) {
                gfr[nf][ks] = ldsfrag(Gs, brr + nf * 16 + l16, ks * 4 + hk);
                ufr[nf][ks] = ldsfrag(Us, brr + nf * 16 + l16, ks * 4 + hk);
            }
        #pragma unroll
        for (int mi = 0; mi < 2; ++mi)
            #pragma unroll
            for (int ks = 0; ks < 2; ++ks)
                afr[mi][ks] = ldsfrag(Ah, arr + mi * 16 + l16, ks * 4 + hk);
        if (t + 1 < nt) {
            stage_half(A + (size_t)bm * K + k1,         &lds[c ^ 1][0][0]);
            stage_half(A + (size_t)(bm + 128) * K + k1, &lds[c ^ 1][1][0]);
        }
        __builtin_amdgcn_s_setprio(1);
        #pragma unroll
        for (int mi = 0; mi < 2; ++mi)
            #pragma unroll
            for (int nf = 0; nf < 4; ++nf)
                #pragma unroll
                for (int ks = 0; ks < 2; ++ks) {
                    ag[mi][nf] = __builtin_amdgcn_mfma_f32_16x16x32_bf16(
                        afr[mi][ks], gfr[nf][ks], ag[mi][nf], 0, 0, 0);
                    au[mi][nf] = __builtin_amdgcn_mfma_f32_16x16x32_bf16(
                        afr[mi][ks], ufr[nf][ks], au[mi][nf], 0, 0, 0);
                }
        __builtin_amdgcn_s_setprio(0);
        __builtin_amdgcn_s_barrier();   // pacing

        #pragma unroll
        for (int mi = 0; mi < 2; ++mi)
            #pragma unroll
            for (int ks = 0; ks < 2; ++ks)
                afr[mi][ks] = ldsfrag(Ah, arr + 32 + mi * 16 + l16, ks * 4 + hk);
        if (t + 1 < nt) {
            stage_half(BG + (size_t)bn * K + k1, &lds[c ^ 1][2][0]);
            stage_half(BU + (size_t)bn * K + k1, &lds[c ^ 1][3][0]);
        }
        __builtin_amdgcn_s_setprio(1);
        #pragma unroll
        for (int mi = 0; mi < 2; ++mi)
            #pragma unroll
            for (int nf = 0; nf < 4; ++nf)
                #pragma unroll
                for (int ks = 0; ks < 2; ++ks) {
                    ag[2 + mi][nf] = __builtin_amdgcn_mfma_f32_16x16x32_bf16(
                        afr[mi][ks], gfr[nf][ks], ag[2 + mi][nf], 0, 0, 0);
                    au[2 + mi][nf] = __builtin_amdgcn_mfma_f32_16x16x32_bf16(
                        afr[mi][ks], ufr[nf][ks], au[2 + mi][nf], 0, 0, 0);
                }
        __builtin_amdgcn_s_setprio(0);

        asm volatile("s_waitcnt vmcnt(0)" ::: "memory");
        __builtin_amdgcn_s_barrier();
    }

    const int r0 = bm + wm * 64 + (lane >> 4) * 4;
    const int c0 = bn + wn * 64 + l16;
    #pragma unroll
    for (int mf = 0; mf < 4; ++mf)
        #pragma unroll
        for (int nf = 0; nf < 4; ++nf)
            #pragma unroll
            for (int r = 0; r < 4; ++r) {
                const float gg = ag[mf][nf][r];
                const float uu = au[mf][nf][r];
                const float v = gg / (1.f + __expf(-gg)) * uu;
                C[(size_t)(r0 + mf * 16 + r) * N + c0 + nf * 16] = __float2bfloat16(v);
            }
}

// ---------------------------------------------------------------------------
// RoPE v2: one wave per 64-dim slice. q_pe slices rotate in place (bf16).
// k_pe slices read from CKV (fp32) and write rope'd values into ALL 16
// heads' Kh[...][128:192] (bf16) — replaces pack_k's k_pe path.
// ---------------------------------------------------------------------------
__global__ __launch_bounds__(256) void rope_kernel(
    bf16* __restrict__ q, const float* __restrict__ ckv,
    bf16* __restrict__ Kh, const int* __restrict__ pos_ids,
    const float* __restrict__ sinT, const float* __restrict__ cosT)
{
    const int wid = blockIdx.x * 4 + (threadIdx.x >> 6);
    const int lane = threadIdx.x & 63;
    const int NQ = BS_ * NH_;

    int bs;
    float x;
    bf16* bptr = nullptr;
    if (wid < NQ) {
        bs = wid >> 4;
        bptr = q + (size_t)wid * QHD_ + NOPE_;
        x = __bfloat162float(bptr[lane]);
    } else {
        bs = wid - NQ;
        x = ckv[(size_t)bs * CKVP_ + KVL_ + lane];
    }
    const int pos = pos_ids[bs];
    const float c  = cosT[pos * ROPE_ + lane];
    const float sn = sinT[pos * ROPE_ + lane];
    const int j = lane & 31;
    const float x0 = __shfl(x, 2 * j);
    const float x1 = __shfl(x, 2 * j + 1);
    const float res = (lane < 32) ? fmaf(x0, c, -x1 * sn) : fmaf(x1, c, x0 * sn);
    if (bptr) {
        bptr[lane] = __float2bfloat16(res);
    } else {
        const int bb = bs >> 11, s = bs & 2047;
        const bf16 rv = __float2bfloat16(res);
        #pragma unroll
        for (int hh = 0; hh < NH_; ++hh)
            Kh[((size_t)(bb * NH_ + hh) * S_ + s) * QHD_ + NOPE_ + lane] = rv;
    }
}

// ---------------------------------------------------------------------------
// pack_vt: Vt (B,NH,128,S) bf16 <- V = KV[...,128:256] fp32, transposed.
// ---------------------------------------------------------------------------
__global__ __launch_bounds__(256) void pack_vt(
    const float* __restrict__ KV, bf16* __restrict__ Vt)
{
    __shared__ float t[32][33];
    const int s0 = blockIdx.x * 32, d0 = blockIdx.y * 32;
    const int bh = blockIdx.z;
    const int tx = threadIdx.x & 31, ty = threadIdx.x >> 5;
    for (int r = ty; r < 32; r += 8)
        t[r][tx] = KV[(((size_t)(bh >> 4) * S_ + s0 + r) * NH_ + (bh & 15)) * KVW_ + NOPE_ + d0 + tx];
    __syncthreads();
    for (int r = ty; r < 32; r += 8)
        Vt[((size_t)bh * VHD_ + d0 + r) * S_ + s0 + tx] = __float2bfloat16(t[tx][r]);
}

// ---------------------------------------------------------------------------
// MFMA flash attention v4 — paired blocks + XCD-chunked heads + no spill.
// ---------------------------------------------------------------------------
__global__ __launch_bounds__(512, 2) void attn_mfma(
    const bf16* __restrict__ Qp, const bf16* __restrict__ Kh,
    const bf16* __restrict__ Vt, bf16* __restrict__ outp)
{
    __shared__ __align__(16) short Ks[64][192];
    __shared__ __align__(16) short Vs[128][64];
    __shared__ __align__(16) short Ps[8][16][64];

    const int tid = threadIdx.x;
    const int wid = tid >> 6, lane = tid & 63;
    const int l16 = lane & 15;
    const int hk  = lane >> 4;
    const int lk  = hk << 3;
    const int pr  = hk << 2;
    const int lx  = l16 & 7;

    const int bid = blockIdx.x;
    const int orig = (bid & 7) * 64 + (bid >> 3);
    const int j  = orig & 15;
    const int gh = orig >> 4;
    const int h = gh & 15, b = gh >> 4;

    const int setB = wid >> 2;
    const int qblk = setB ? (31 - j) : j;
    const int qw = qblk * 64 + (wid & 3) * 16;
    const int myNt = qblk + 1;
    const int ntStage = 32 - j;

    short8_t qf[6];
    const bf16* qbase = Qp + (((size_t)b * S_ + qw + l16) * NH_ + h) * QHD_;
    #pragma unroll
    for (int kk = 0; kk < 6; ++kk)
        qf[kk] = *(const short8_t*)(qbase + kk * 32 + lk);

    const bf16* Khb = Kh + (size_t)(b * NH_ + h) * S_ * QHD_;
    const bf16* Vtb = Vt + (size_t)(b * NH_ + h) * VHD_ * S_;

    f32x4 o[8] = {};
    float mr[4] = {-3.0e38f, -3.0e38f, -3.0e38f, -3.0e38f};
    float lr[4] = {0.f, 0.f, 0.f, 0.f};
    const float scale = 0.07216878364870323f;

    const int krow = tid >> 3, kc0 = (tid & 7) * 3;
    const int vrow = tid >> 2, vc0 = (tid & 3) * 2;

    short8_t kreg[3], vreg[2];
    auto load_tile = [&](int kt) {
        const short* ksrc = (const short*)(Khb + ((size_t)(kt * 64 + krow)) * QHD_);
        kreg[0] = *(const short8_t*)(ksrc + (kc0 + 0) * 8);
        kreg[1] = *(const short8_t*)(ksrc + (kc0 + 1) * 8);
        kreg[2] = *(const short8_t*)(ksrc + (kc0 + 2) * 8);
        const short* vsrc = (const short*)(Vtb + (size_t)vrow * S_ + kt * 64);
        vreg[0] = *(const short8_t*)(vsrc + (vc0 + 0) * 8);
        vreg[1] = *(const short8_t*)(vsrc + (vc0 + 1) * 8);
    };
    auto write_tile = [&]() {
        const int kx = krow & 7, vx = vrow & 7;
        *(short8_t*)&Ks[krow][((kc0 + 0) ^ kx) << 3] = kreg[0];
        *(short8_t*)&Ks[krow][((kc0 + 1) ^ kx) << 3] = kreg[1];
        *(short8_t*)&Ks[krow][((kc0 + 2) ^ kx) << 3] = kreg[2];
        *(short8_t*)&Vs[vrow][((vc0 + 0) ^ vx) << 3] = vreg[0];
        *(short8_t*)&Vs[vrow][((vc0 + 1) ^ vx) << 3] = vreg[1];
    };

    load_tile(0);

    for (int t = 0; t < ntStage; ++t) {
        write_tile();
        __syncthreads();
        if (t + 1 < ntStage) load_tile(t + 1);
        if (t < myNt) {
            const int k0 = t << 6;
            f32x4 s[4] = {};
            #pragma unroll
            for (int kk = 0; kk < 6; ++kk) {
                #pragma unroll
                for (int n = 0; n < 4; ++n) {
                    short8_t kf = *(const short8_t*)&Ks[n * 16 + l16][((kk * 4 + hk) ^ lx) << 3];
                    s[n] = __builtin_amdgcn_mfma_f32_16x16x32_bf16(qf[kk], kf, s[n], 0, 0, 0);
                }
            }
            if (t == myNt - 1) {
                #pragma unroll
                for (int n = 0; n < 4; ++n) {
                    const int kg = k0 + n * 16 + l16;
                    #pragma unroll
                    for (int r = 0; r < 4; ++r) {
                        if (kg > qw + pr + r) s[n][r] = -3.0e38f;
                    }
                }
            }
            #pragma unroll
            for (int r = 0; r < 4; ++r) {
                float rm = fmaxf(fmaxf(s[0][r], s[1][r]), fmaxf(s[2][r], s[3][r]));
                rm = fmaxf(rm, __shfl_xor(rm, 1));
                rm = fmaxf(rm, __shfl_xor(rm, 2));
                rm = fmaxf(rm, __shfl_xor(rm, 4));
                rm = fmaxf(rm, __shfl_xor(rm, 8));
                const float mnew = fmaxf(mr[r], rm);
                const float corr = __expf((mr[r] - mnew) * scale);
                mr[r] = mnew;
                float rs = 0.f;
                #pragma unroll
                for (int n = 0; n < 4; ++n) {
                    const float p = __expf((s[n][r] - mnew) * scale);
                    s[n][r] = p;
                    rs += p;
                }
                rs += __shfl_xor(rs, 1);
                rs += __shfl_xor(rs, 2);
                rs += __shfl_xor(rs, 4);
                rs += __shfl_xor(rs, 8);
                lr[r] = lr[r] * corr + rs;
                #pragma unroll
                for (int n = 0; n < 8; ++n) o[n][r] *= corr;
            }
            #pragma unroll
            for (int n = 0; n < 4; ++n) {
                #pragma unroll
                for (int r = 0; r < 4; ++r) {
                    union { bf16 hh; short u; } cv;
                    cv.hh = __float2bfloat16(s[n][r]);
                    const int row = pr + r;
                    const int col = (((n * 2 + (l16 >> 3)) ^ (row & 7)) << 3) + (l16 & 7);
                    Ps[wid][row][col] = cv.u;
                }
            }
            #pragma unroll
            for (int kk2 = 0; kk2 < 2; ++kk2) {
                short8_t pf = *(const short8_t*)&Ps[wid][l16][((kk2 * 4 + hk) ^ lx) << 3];
                #pragma unroll
                for (int n = 0; n < 8; ++n) {
                    short8_t vf = *(const short8_t*)&Vs[n * 16 + l16][((kk2 * 4 + hk) ^ lx) << 3];
                    o[n] = __builtin_amdgcn_mfma_f32_16x16x32_bf16(pf, vf, o[n], 0, 0, 0);
                }
            }
        }
        __syncthreads();
    }

    float inv[4];
    #pragma unroll
    for (int r = 0; r < 4; ++r) inv[r] = 1.f / lr[r];
    bf16* ob = outp + (((size_t)b * S_ + qw + pr) * NH_ + h) * VHD_;
    #pragma unroll
    for (int r = 0; r < 4; ++r)
        #pragma unroll
        for (int n = 0; n < 8; ++n)
            ob[(size_t)r * (NH_ * VHD_) + n * 16 + l16] = __float2bfloat16(o[n][r] * inv[r]);
}

// ---------------------------------------------------------------------------
// Launch
// ---------------------------------------------------------------------------
extern "C" void kernel_launch(void* const* d_in, const int* in_sizes, int n_in,
                              void* d_out, int out_size, void* d_ws, size_t ws_size,
                              hipStream_t stream)
{
    const float* hidden  = (const float*)d_in[0];
    const float* ln1_w   = (const float*)d_in[1];
    const float* q_a_k   = (const float*)d_in[2];
    const float* q_a_ln  = (const float*)d_in[3];
    const float* q_b_k   = (const float*)d_in[4];
    const float* kv_a_k  = (const float*)d_in[5];
    const float* kv_a_ln = (const float*)d_in[6];
    const float* kv_b_k  = (const float*)d_in[7];
    const float* o_k     = (const float*)d_in[8];
    const float* ln2_w   = (const float*)d_in[9];
    const float* gate_k  = (const float*)d_in[10];
    const float* up_k    = (const float*)d_in[11];
    const float* down_k  = (const float*)d_in[12];
    const float* sinT    = (const float*)d_in[13];
    const float* cosT    = (const float*)d_in[14];
    const int*   pos     = (const int*)d_in[15];
    float* out = (float*)d_out;
    char* ws = (char*)d_ws;

    // ---- Phase-1 workspace layout ----
    bf16* qaT   = (bf16*)(ws + 0);            // [1536][2048]  6,291,456
    bf16* qbT   = (bf16*)(ws + 6291456);      // [3072][1536]  9,437,184
    bf16* kvaT  = (bf16*)(ws + 15728640);     // [640][2048]   2,621,440
    bf16* kvbT  = (bf16*)(ws + 18350080);     // [4096][512]   4,194,304
    bf16* oT    = (bf16*)(ws + 22544384);     // [2048][2048]  8,388,608
    bf16* Xb    = (bf16*)(ws + 30932992);     // [4096][2048] 16,777,216
    bf16* QAb   = (bf16*)(ws + 47710208);     // [4096][1536] 12,582,912
    bf16* CKVNb = (bf16*)(ws + 60293120);     // [4096][512]   4,194,304
    bf16* Qb    = (bf16*)(ws + 64487424);     // [4096][3072] 25,165,824
    float* CKV  = (float*)(ws + 89653248);    // [4096][640]  10,485,760
    float* KV   = (float*)(ws + 100139008);   // [4096][4096] 67,108,864
    bf16* ATTNb = (bf16*)(ws + 167247872);    // [4096][2048] 16,777,216
    bf16* Vt    = (bf16*)(ws + 0);            // overlays dead qaT/qbT/kvaT
    bf16* Kh    = (bf16*)(ws + 30932992);     // overlays dead Xb+QAb(part)
    // ---- Phase-2 layout ----
    bf16* gateT = (bf16*)(ws + 0);            // [8192][2048] 33,554,432
    bf16* upT   = (bf16*)(ws + 33554432);     // [8192][2048] 33,554,432
    bf16* downT = (bf16*)(ws + 67108864);     // [2048][8192] 33,554,432
    bf16* X2b   = (bf16*)(ws + 100663296);    // [4096][2048] 16,777,216
    bf16* MLPb  = (bf16*)(ws + 117440512);    // [4096][8192] 67,108,864

    const dim3 tb(32, 8);

    // 0. weight transposes (attention-phase weights)
    transp_bf16<<<dim3(1536 / 32, 2048 / 32), tb, 0, stream>>>(q_a_k, qaT, 2048, 1536, 1536);
    transp_bf16<<<dim3(3072 / 32, 1536 / 32), tb, 0, stream>>>(q_b_k, qbT, 1536, 3072, 3072);
    transp_bf16<<<dim3(640 / 32, 2048 / 32), tb, 0, stream>>>(kv_a_k, kvaT, 2048, 576, 640);
    transp_bf16<<<dim3(4096 / 32, 512 / 32), tb, 0, stream>>>(kv_b_k, kvbT, 512, 4096, 4096);
    transp_bf16<<<dim3(2048 / 32, 2048 / 32), tb, 0, stream>>>(o_k, oT, 2048, 2048, 2048);

    // 1. Xb = rmsnorm(hidden)
    rmsnorm2<float, bf16><<<BS_, 256, 0, stream>>>(hidden, ln1_w, Xb, H_, H_, H_);
    // 2. QAb = Xb @ qaT   (n128 v2, grid 12x16)
    gemm256n128<0, bf16><<<dim3(QL_ / 128, BS_ / 256), 512, 0, stream>>>(
        Xb, qaT, nullptr, nullptr, QAb, BS_, QL_, H_);
    // 3. QAb = rmsnorm(QAb) in place
    rmsnorm2<bf16, bf16><<<BS_, 256, 0, stream>>>(QAb, q_a_ln, QAb, QL_, QL_, QL_);
    // 4. Qb = QAb @ qbT   (n128 v2, grid 24x16)
    gemm256n128<0, bf16><<<dim3((NH_ * QHD_) / 128, BS_ / 256), 512, 0, stream>>>(
        QAb, qbT, nullptr, nullptr, Qb, BS_, NH_ * QHD_, QL_);
    // 5. CKV = Xb @ kvaT (fp32, padded width 640; 128-tile)
    gemm_bf16<0, float><<<dim3(CKVP_ / 128, BS_ / 128), 256, 0, stream>>>(
        Xb, kvaT, nullptr, nullptr, CKV, BS_, CKVP_, H_);
    // 6. CKVNb = rmsnorm(CKV[:, :512])
    rmsnorm2<float, bf16><<<BS_, 256, 0, stream>>>(CKV, kv_a_ln, CKVNb, KVL_, CKVP_, KVL_);
    // 7. KV/Kh = CKVNb @ kvbT (MODE 3: k_nope -> Kh bf16, v -> KV fp32)
    gemm256<3, float><<<dim3((NH_ * KVW_) / 256, BS_ / 256), 512, 0, stream>>>(
        CKVNb, kvbT, nullptr, nullptr, KV, Kh, BS_, NH_ * KVW_, KVL_);
    // 8. RoPE: q_pe in place; k_pe -> Kh[*][128:192] for all heads
    rope_kernel<<<(BS_ * NH_ + BS_) / 4, 256, 0, stream>>>(Qb, CKV, Kh, pos, sinT, cosT);
    // 9. pack V^T (bf16 transposed)
    pack_vt<<<dim3(S_ / 32, VHD_ / 32, B_ * NH_), 256, 0, stream>>>(KV, Vt);
    // 10. MFMA flash attention -> ATTNb
    attn_mfma<<<dim3(512), 512, 0, stream>>>(Qb, Kh, Vt, ATTNb);
    // 11. d_out = ATTNb @ oT + hidden (fp32, n128 v2, grid 16x16)
    gemm256n128<1, float><<<dim3(H_ / 128, BS_ / 256), 512, 0, stream>>>(
        ATTNb, oT, hidden, nullptr, out, BS_, H_, NH_ * VHD_);

    // 12. MLP-phase weight transposes
    transp_bf16<<<dim3(8192 / 32, 2048 / 32), tb, 0, stream>>>(gate_k, gateT, 2048, 8192, 8192);
    transp_bf16<<<dim3(8192 / 32, 2048 / 32), tb, 0, stream>>>(up_k, upT, 2048, 8192, 8192);
    transp_bf16<<<dim3(2048 / 32, 8192 / 32), tb, 0, stream>>>(down_k, downT, 8192, 2048, 2048);

    // 13. X2b = rmsnorm(d_out)
    rmsnorm2<float, bf16><<<BS_, 256, 0, stream>>>(out, ln2_w, X2b, H_, H_, H_);
    // 14. MLPb = silu(X2b @ gateT) * (X2b @ upT)  — fused dual GEMM (v2)
    gemm256dual<<<dim3(FF_ / 128, BS_ / 256), 512, 0, stream>>>(
        X2b, gateT, upT, MLPb, BS_, FF_, H_);
    // 15. d_out = MLPb @ downT + d_out (n128 v2, grid 16x16)
    gemm256n128<1, float><<<dim3(H_ / 128, BS_ / 256), 512, 0, stream>>>(
        MLPb, downT, out, nullptr, out, BS_, H_, FF_);
}